// Round 12
// baseline (138.074 us; speedup 1.0000x reference)
//
#include <hip/hip_runtime.h>
#include <hip/hip_bf16.h>
#include <math.h>
#include <stdint.h>

#define H_ 16
#define N_ 4096
#define NT_ 4064        // tail length
#define NL_ 2032        // LSH segment length
#define SINK_ 32
#define SAMP_ 256
#define SCALE_ 0.125f
#define QSCALE_ 0.18033688f    // 0.125 * log2(e)
#define M0L2_ 11.5415606f      // 8 * log2(e)
#define M0_ 8.0f
#define NEGBIG_ -3.0e38f
#define LOGOFF_L2_ 2.9886841f  // log2(2032/256)

typedef unsigned int uint;
typedef unsigned short ushort;
typedef short bf16x8 __attribute__((ext_vector_type(8)));
typedef float f32x4 __attribute__((ext_vector_type(4)));

union B8 { uint4 u; bf16x8 b; };

__device__ __forceinline__ f32x4 mfma16(const B8& a, const B8& b, f32x4 c) {
  return __builtin_amdgcn_mfma_f32_16x16x32_bf16(a.b, b.b, c, 0, 0, 0);
}

__device__ __forceinline__ uint bfpack(float a, float b) {
  uint ua = __float_as_uint(a), ub = __float_as_uint(b);
  ua += 0x7fffu + ((ua >> 16) & 1u);
  ub += 0x7fffu + ((ub >> 16) & 1u);
  return (ua >> 16) | (ub & 0xffff0000u);
}

__device__ __forceinline__ uint cvtpk(float a, float b) {
  union { __hip_bfloat162 h; uint u; } r;
  r.h.x = __float2bfloat16(a);
  r.h.y = __float2bfloat16(b);
  return r.u;
}

__device__ __forceinline__ float logaddexpf_(float a, float b) {
  float mx = fmaxf(a, b);
  return mx + __logf(__expf(a - mx) + __expf(b - mx));
}

__device__ __forceinline__ uint32_t rotl32_(uint32_t v, uint32_t d) {
  return (v << d) | (v >> (32u - d));
}

// JAX threefry2x32 (20 rounds)
__device__ inline void tf2x32(uint32_t k0, uint32_t k1, uint32_t& x0, uint32_t& x1) {
  uint32_t ks2 = k0 ^ k1 ^ 0x1BD11BDAu;
  x0 += k0; x1 += k1;
#define TFR(r) { x0 += x1; x1 = rotl32_(x1, r); x1 ^= x0; }
  TFR(13u) TFR(15u) TFR(26u) TFR(6u)
  x0 += k1;  x1 += ks2 + 1u;
  TFR(17u) TFR(29u) TFR(16u) TFR(24u)
  x0 += ks2; x1 += k0 + 2u;
  TFR(13u) TFR(15u) TFR(26u) TFR(6u)
  x0 += k0;  x1 += k1 + 3u;
  TFR(17u) TFR(29u) TFR(16u) TFR(24u)
  x0 += k1;  x1 += ks2 + 4u;
  TFR(13u) TFR(15u) TFR(26u) TFR(6u)
  x0 += ks2; x1 += k0 + 5u;
#undef TFR
}

// ---------------- fixed-offset softmax ----------------
__device__ __forceinline__ void nomax_sm(f32x4 s[4], float& ssum) {
#pragma unroll
  for (int st = 0; st < 4; ++st)
#pragma unroll
    for (int r = 0; r < 4; ++r) {
      s[st][r] = __builtin_exp2f(s[st][r]);
      ssum += s[st][r];
    }
}

// ---------------- PV (lsh layout): vv rows stride 144, linear pbuf ----------------
__device__ __forceinline__ void pv144(const f32x4 s[4], f32x4 o[4],
                                      const char* vbase, char* pw, int g) {
  __builtin_amdgcn_s_setprio(1);
#pragma unroll
  for (int hk2 = 0; hk2 < 2; ++hk2) {
    const f32x4 pa = s[2 * hk2], pc = s[2 * hk2 + 1];
    *(uint2*)(pw + 8 * g)      = make_uint2(cvtpk(pa[0], pa[1]), cvtpk(pa[2], pa[3]));
    *(uint2*)(pw + 32 + 8 * g) = make_uint2(cvtpk(pc[0], pc[1]), cvtpk(pc[2], pc[3]));
    B8 pf, vf;
    pf.u = *(const uint4*)(pw + g * 16);
    vf.u = *(const uint4*)(vbase + 0 * 2304 + hk2 * 64); o[0] = mfma16(vf, pf, o[0]);
    vf.u = *(const uint4*)(vbase + 1 * 2304 + hk2 * 64); o[1] = mfma16(vf, pf, o[1]);
    vf.u = *(const uint4*)(vbase + 2 * 2304 + hk2 * 64); o[2] = mfma16(vf, pf, o[2]);
    vf.u = *(const uint4*)(vbase + 3 * 2304 + hk2 * 64); o[3] = mfma16(vf, pf, o[3]);
  }
  __builtin_amdgcn_s_setprio(0);
}

// =========================================================================
// pack: blocks 0..2047 K bf16 linear; 2048..3071 V transpose; 3072..3327 hash.
// =========================================================================
__global__ __launch_bounds__(256) void kern_packhash(
    const float* __restrict__ K, const float* __restrict__ V, const float* __restrict__ Q,
    const float* __restrict__ proj,
    ushort* __restrict__ Kb, ushort* __restrict__ Vb, ushort* __restrict__ Vt,
    int* __restrict__ hq, int* __restrict__ hk) {
  const int bb = blockIdx.x;
  const int tid = threadIdx.x;
  if (bb < 2048) {               // ---- K linear pack ----
    const size_t idx = (size_t)bb * 256 + tid;
    const float4* s = (const float4*)(K + idx * 8);
    float4 f0 = s[0], f1 = s[1];
    uint4 p = make_uint4(bfpack(f0.x, f0.y), bfpack(f0.z, f0.w),
                         bfpack(f1.x, f1.y), bfpack(f1.z, f1.w));
    *(uint4*)(Kb + idx * 8) = p;
    return;
  }
  if (bb < 3072) {               // ---- V transpose + row pack ----
    __shared__ ushort tr[64 * 72];
    const int u = bb - 2048;
    const int h = u >> 6, nt = u & 63;
    const int n0 = nt * 64;
    const size_t hN = (size_t)h * N_;
    const int nloc = tid >> 2, dpart = (tid & 3) * 16;
    const float4* src = (const float4*)(V + (hN + n0 + nloc) * 64 + dpart);
    float4 f0 = src[0], f1 = src[1], f2 = src[2], f3 = src[3];
    uint p0 = bfpack(f0.x, f0.y), p1 = bfpack(f0.z, f0.w);
    uint p2 = bfpack(f1.x, f1.y), p3 = bfpack(f1.z, f1.w);
    uint p4 = bfpack(f2.x, f2.y), p5 = bfpack(f2.z, f2.w);
    uint p6 = bfpack(f3.x, f3.y), p7 = bfpack(f3.z, f3.w);
    ushort* vbdst = Vb + (hN + n0 + nloc) * 64 + dpart;
    ((uint4*)vbdst)[0] = make_uint4(p0, p1, p2, p3);
    ((uint4*)vbdst)[1] = make_uint4(p4, p5, p6, p7);
    uint pv[8] = {p0, p1, p2, p3, p4, p5, p6, p7};
#pragma unroll
    for (int j = 0; j < 8; ++j) {
      tr[(dpart + 2 * j    ) * 72 + nloc] = (ushort)(pv[j] & 0xffffu);
      tr[(dpart + 2 * j + 1) * 72 + nloc] = (ushort)(pv[j] >> 16);
    }
    __syncthreads();
    const int d = tid >> 2, np = (tid & 3) * 16;
    const uint4* tp = (const uint4*)(tr + d * 72 + np);
    uint4 t0 = tp[0], t1 = tp[1];
    ushort* dst = Vt + ((size_t)(h * 64 + d)) * 4096 + n0 + np;
    ((uint4*)dst)[0] = t0;
    ((uint4*)dst)[1] = t1;
    return;
  }
  // ---- hash ----
  __shared__ float pr[448];
  const int u = bb - 3072;
  const int h = u & 15, tile = (u >> 4) & 7, which = u >> 7;
  for (int t = tid; t < 448; t += 256) pr[t] = proj[t];
  __syncthreads();
  const int i = tile * 256 + tid;
  if (i >= NL_) return;
  const int orig = (which == 0) ? (SINK_ + NL_ + i) : (SINK_ + i);
  const float4* x = (const float4*)((which == 0 ? Q : K) + ((size_t)h * N_ + orig) * 64);
  float xr[64];
#pragma unroll
  for (int d = 0; d < 16; ++d) {
    float4 g = x[d];
    xr[4*d+0] = g.x; xr[4*d+1] = g.y; xr[4*d+2] = g.z; xr[4*d+3] = g.w;
  }
  int bin = 0;
#pragma unroll
  for (int r = 0; r < 7; ++r) {
    float acc = 0.f;
#pragma unroll
    for (int d = 0; d < 64; ++d) acc = fmaf(xr[d], pr[d * 7 + r], acc);
    if (acc > 0.f) bin |= (1 << r);
  }
  const int g = bin ^ (bin >> 1);
  (which == 0 ? hq : hk)[h * NL_ + i] = g;
}

// ---------------- chunked stable counting sort + threefry sample ----------------
__global__ __launch_bounds__(256) void kern_sortsamp(
    const int* __restrict__ hq, const int* __restrict__ hk,
    int* __restrict__ q_sort, int* __restrict__ k_sort,
    int* __restrict__ samp_pos, int* __restrict__ samp_orig) {
  const int h = blockIdx.x, which = blockIdx.y;
  const int tid = threadIdx.x;

  __shared__ unsigned char keys8[NL_];
  __shared__ ushort M[64 * 130];
  __shared__ int btot[128];
  __shared__ int bscan[128];
  __shared__ ushort srt[NL_];

  const int* src = (which == 0 ? hq : hk) + h * NL_;
  for (int u = tid; u < 64 * 130 / 2; u += 256) ((uint*)M)[u] = 0u;
  for (int u = tid; u < NL_; u += 256) keys8[u] = (unsigned char)src[u];
  __syncthreads();

  if (tid < 64) {
    const int c = tid;
#pragma unroll 4
    for (int j = 0; j < 32; ++j) {
      const int u = c * 32 + j;
      if (u < NL_) ++M[c * 130 + keys8[u]];
    }
  }
  __syncthreads();

  if (tid < 128) {
    const int b = tid;
    int run = 0;
    for (int c = 0; c < 64; ++c) {
      const int v = M[c * 130 + b];
      M[c * 130 + b] = (ushort)run;
      run += v;
    }
    btot[b] = run;
    bscan[b] = run;
  }
  __syncthreads();

  for (int ofs = 1; ofs < 128; ofs <<= 1) {
    int v = 0;
    if (tid < 128 && tid >= ofs) v = bscan[tid - ofs];
    __syncthreads();
    if (tid < 128) bscan[tid] += v;
    __syncthreads();
  }

  int* dst = (which == 0 ? q_sort : k_sort) + h * NL_;
  if (tid < 64) {
    const int c = tid;
    for (int j = 0; j < 32; ++j) {
      const int u = c * 32 + j;
      if (u < NL_) {
        const int k = keys8[u];
        const int pos = (bscan[k] - btot[k]) + M[c * 130 + k];
        M[c * 130 + k] += 1;
        dst[pos] = u;
        srt[pos] = (ushort)u;
      }
    }
  }
  __syncthreads();

  if (which == 1) {
    const int s = tid;
    uint32_t a0 = 0u, a1 = 0u; tf2x32(0u, 1234u, a0, a1);
    uint32_t b0 = 0u, b1 = 0u; tf2x32(a0, a1, b0, b1);
    uint32_t c0 = 0u, c1 = 1u; tf2x32(a0, a1, c0, c1);
    const uint32_t j = (uint32_t)(h * SAMP_ + s);
    uint32_t h0 = 0u, h1 = j; tf2x32(b0, b1, h0, h1);
    uint32_t l0 = 0u, l1 = j; tf2x32(c0, c1, l0, l1);
    const uint32_t Hb = h0 ^ h1, Lb = l0 ^ l1;
    const uint32_t off = ((Hb % 2032u) * 16u + (Lb % 2032u)) % 2032u;
    samp_pos[h * SAMP_ + s] = (int)off;
    samp_orig[h * SAMP_ + s] = (int)srt[off];
  }
}

// =========================================================================
// MFMA flash attention. Grid 1280, every block <= 4 tiles (load-balanced):
//  [0,512)    : P2 split-K halves (4 tiles).
//  [512,768)  : P1 half0 dense  (qt 4..7, keys [0,512), NO mask, 4 tiles) -> tail.
//  [768,1024) : P1 half1 causal (qt desc 7..4, keys [512,1016), 4..1 tiles) -> attn4.
//  [1024,1280): P1 small causal (qt desc 3..0, 4..1 tiles) -> tail.
// LDS: kk 18432 + vv 17408 + pbuf 5120 = 40960 B -> 4 blocks/CU.
// =========================================================================
__global__ __launch_bounds__(256) void kern_attn_mfma(
    const float* __restrict__ Q, const ushort* __restrict__ Kb, const ushort* __restrict__ Vt,
    float* __restrict__ tail_attn, float* __restrict__ tail_lse,
    float* __restrict__ attn2, float* __restrict__ lse2,
    float* __restrict__ attn4, float* __restrict__ lse4) {
  __shared__ uint kk[4608];    // 18432 B
  __shared__ uint vv[4352];    // 17408 B
  __shared__ uint pbuf[1280];  // 5120 B

  const int b = blockIdx.x;
  const int tid = threadIdx.x;
  const int lane = tid & 63, w = tid >> 6;
  const int g = lane >> 4, q = lane & 15;
  const uint4 z4 = make_uint4(0, 0, 0, 0);
  const f32x4 accb = {-M0L2_, -M0L2_, -M0L2_, -M0L2_};

  // outmode: 0 = tail_attn, 1 = attn2(p2slot), 2 = attn4
  int h, q0, qbase, kbase, ntiles, klen, koff = 0, p2slot = 0, chunkc = 0, outmode;
  bool causal;
  if (b < 512) {                       // P2 split-K halves
    const int u = b; const int vh = u & 31; const int qt = (u >> 5) & 7;
    const int hf = u >> 8;
    h = vh >> 1; const int pp = vh & 1;
    q0 = qt * 128;
    qbase = SINK_ + pp * 2032 + 1016;
    kbase = SINK_ + pp * 2032 + hf * 512;
    ntiles = 4; causal = false; klen = hf ? 504 : 512;
    p2slot = hf * 32 * 1016 + vh * 1016;
    outmode = 1;
  } else if (b < 768) {                // P1 half0 dense (maskless)
    const int u = b - 512; const int vh = u & 63;
    const int qt = 4 + (u >> 6);
    h = vh >> 2; chunkc = vh & 3;
    q0 = qt * 128;
    qbase = SINK_ + chunkc * 1016;
    kbase = qbase;
    ntiles = 4; causal = false; klen = 512;
    outmode = 0;
  } else if (b < 1024) {               // P1 half1 causal (keys 512..1015), qt desc
    const int u = b - 768; const int vh = u & 63;
    const int qt = 7 - (u >> 6);
    h = vh >> 2; chunkc = vh & 3;
    q0 = qt * 128;
    qbase = SINK_ + chunkc * 1016;
    kbase = qbase + 512;
    ntiles = qt - 3; causal = true; klen = 504; koff = 512;
    outmode = 2;
  } else {                             // P1 small causal, qt desc 3..0
    const int u = b - 1024; const int vh = u & 63;
    const int qt = 3 - (u >> 6);
    h = vh >> 2; chunkc = vh & 3;
    q0 = qt * 128;
    qbase = SINK_ + chunkc * 1016;
    kbase = qbase;
    ntiles = qt + 1; causal = true; klen = 1016;
    outmode = 0;
  }
  const size_t hN = (size_t)h * N_;
  const int qrowA = q0 + w * 16 + q;
  const int qrowB = qrowA + 64;
  const int qcA = min(qrowA, 1015), qcB = min(qrowB, 1015);
  const int qeA = qrowA - koff, qeB = qrowB - koff;        // effective rows vs local keys
  const int qwA_lo = q0 + w * 16 - koff, qwmaxA = qwA_lo + 15;
  const int qwB_lo = qwA_lo + 64;

  B8 qbA0, qbA1, qbB0, qbB1;
  {
    const float4* qp = (const float4*)(Q + (hN + qbase + qcA) * 64);
    float4 a = qp[2*g], c = qp[2*g+1], d = qp[8+2*g], e = qp[8+2*g+1];
    qbA0.u = make_uint4(bfpack(a.x*QSCALE_, a.y*QSCALE_), bfpack(a.z*QSCALE_, a.w*QSCALE_),
                        bfpack(c.x*QSCALE_, c.y*QSCALE_), bfpack(c.z*QSCALE_, c.w*QSCALE_));
    qbA1.u = make_uint4(bfpack(d.x*QSCALE_, d.y*QSCALE_), bfpack(d.z*QSCALE_, d.w*QSCALE_),
                        bfpack(e.x*QSCALE_, e.y*QSCALE_), bfpack(e.z*QSCALE_, e.w*QSCALE_));
    const float4* qp2 = (const float4*)(Q + (hN + qbase + qcB) * 64);
    a = qp2[2*g]; c = qp2[2*g+1]; d = qp2[8+2*g]; e = qp2[8+2*g+1];
    qbB0.u = make_uint4(bfpack(a.x*QSCALE_, a.y*QSCALE_), bfpack(a.z*QSCALE_, a.w*QSCALE_),
                        bfpack(c.x*QSCALE_, c.y*QSCALE_), bfpack(c.z*QSCALE_, c.w*QSCALE_));
    qbB1.u = make_uint4(bfpack(d.x*QSCALE_, d.y*QSCALE_), bfpack(d.z*QSCALE_, d.w*QSCALE_),
                        bfpack(e.x*QSCALE_, e.y*QSCALE_), bfpack(e.z*QSCALE_, e.w*QSCALE_));
  }
  f32x4 oA[4] = {{0,0,0,0},{0,0,0,0},{0,0,0,0},{0,0,0,0}};
  f32x4 oB[4] = {{0,0,0,0},{0,0,0,0},{0,0,0,0},{0,0,0,0}};
  float ssA = 0.f, ssB = 0.f;

  const int krow_l = tid >> 1, kpart = tid & 1;
  const int vrow = tid >> 2, vc32 = tid & 3;
  char* kdst = (char*)kk + krow_l * 144 + kpart * 64;
  char* vdst = (char*)vv + vrow * 272 + vc32 * 64;
  const char* kq = (const char*)kk + q * 144 + g * 16;
  const char* vq = (const char*)vv + q * 272 + g * 16;
  char* pw = (char*)pbuf + w * 1280 + q * 80;
  const size_t vtbase = ((size_t)(h * 64 + vrow)) * 4096 + kbase + vc32 * 32;

  uint4 kp0, kp1, kp2, kp3, va, va2, vb_, vb2;

#define LOADK(T) { const int kr = (T) * 128 + krow_l; \
    if (kr < klen) { const uint4* s = (const uint4*)(Kb + (hN + kbase + kr) * 64 + kpart * 32); \
      kp0 = s[0]; kp1 = s[1]; kp2 = s[2]; kp3 = s[3]; } \
    else { kp0 = z4; kp1 = z4; kp2 = z4; kp3 = z4; } }
#define LOADV(T) { const uint4* sv = (const uint4*)(Vt + vtbase + (size_t)(T) * 128); \
    va = sv[0]; va2 = sv[1]; vb_ = sv[2]; vb2 = sv[3]; }

  LOADK(0) LOADV(0)

  for (int t = 0; t < ntiles; ++t) {
    const int kt = t * 128;
    __syncthreads();
    *(uint4*)kdst = kp0; *(uint4*)(kdst + 16) = kp1;
    *(uint4*)(kdst + 32) = kp2; *(uint4*)(kdst + 48) = kp3;
    *(uint4*)vdst = va; *(uint4*)(vdst + 16) = va2;
    *(uint4*)(vdst + 32) = vb_; *(uint4*)(vdst + 48) = vb2;
    __syncthreads();
    if (t + 1 < ntiles) { LOADK(t + 1) LOADV(t + 1) }

#pragma unroll
    for (int u2 = 0; u2 < 2; ++u2) {
      const int hb = kt + u2 * 64;
      const bool dA = !(causal && hb > qwmaxA);
      f32x4 sA[4], sB[4];
      __builtin_amdgcn_s_setprio(1);
#pragma unroll
      for (int st = 0; st < 4; ++st) {
        B8 ka, kb2;
        ka.u  = *(const uint4*)(kq + (u2 * 64 + st * 16) * 144);
        kb2.u = *(const uint4*)(kq + (u2 * 64 + st * 16) * 144 + 64);
        if (dA) {
          f32x4 acc = accb;
          acc = mfma16(ka, qbA0, acc); acc = mfma16(kb2, qbA1, acc);
          sA[st] = acc;
        }
        f32x4 acc2 = accb;
        acc2 = mfma16(ka, qbB0, acc2); acc2 = mfma16(kb2, qbB1, acc2);
        sB[st] = acc2;
      }
      __builtin_amdgcn_s_setprio(0);

      if (causal) {
        const int kb0 = hb + 4 * g;
        if (dA && hb + 63 > qwA_lo) {
#pragma unroll
          for (int st = 0; st < 4; ++st)
#pragma unroll
            for (int r = 0; r < 4; ++r)
              if (kb0 + st * 16 + r > qeA) sA[st][r] = NEGBIG_;
        }
        if (hb + 63 > qwB_lo) {
#pragma unroll
          for (int st = 0; st < 4; ++st)
#pragma unroll
            for (int r = 0; r < 4; ++r)
              if (kb0 + st * 16 + r > qeB) sB[st][r] = NEGBIG_;
        }
      } else if (hb + 63 >= klen) {
        const int kb0 = hb + 4 * g;
#pragma unroll
        for (int st = 0; st < 4; ++st)
#pragma unroll
          for (int r = 0; r < 4; ++r)
            if (kb0 + st * 16 + r >= klen) { sA[st][r] = NEGBIG_; sB[st][r] = NEGBIG_; }
      }

#define PVX(SS, OO) { \
      __builtin_amdgcn_s_setprio(1); \
      _Pragma("unroll") \
      for (int hk2 = 0; hk2 < 2; ++hk2) { \
        const f32x4 pa = SS[2 * hk2], pc = SS[2 * hk2 + 1]; \
        *(uint2*)(pw + 8 * g)      = make_uint2(cvtpk(pa[0], pa[1]), cvtpk(pa[2], pa[3])); \
        *(uint2*)(pw + 32 + 8 * g) = make_uint2(cvtpk(pc[0], pc[1]), cvtpk(pc[2], pc[3])); \
        B8 pf, vf; \
        pf.u = *(const uint4*)(pw + g * 16); \
        const int vo = u2 * 128 + hk2 * 64; \
        vf.u = *(const uint4*)(vq + 0 * 4352 + vo); OO[0] = mfma16(vf, pf, OO[0]); \
        vf.u = *(const uint4*)(vq + 1 * 4352 + vo); OO[1] = mfma16(vf, pf, OO[1]); \
        vf.u = *(const uint4*)(vq + 2 * 4352 + vo); OO[2] = mfma16(vf, pf, OO[2]); \
        vf.u = *(const uint4*)(vq + 3 * 4352 + vo); OO[3] = mfma16(vf, pf, OO[3]); \
      } \
      __builtin_amdgcn_s_setprio(0); }

      if (dA) {
        nomax_sm(sA, ssA);
        PVX(sA, oA)
      }
      nomax_sm(sB, ssB);
      PVX(sB, oB)
#undef PVX
    }
  }
#undef LOADK
#undef LOADV

  ssA += __shfl_xor(ssA, 16); ssA += __shfl_xor(ssA, 32);
  ssB += __shfl_xor(ssB, 16); ssB += __shfl_xor(ssB, 32);
#pragma unroll
  for (int fr = 0; fr < 2; ++fr) {
    const int qrow = fr == 0 ? qrowA : qrowB;
    if (qrow >= 1016) continue;
    f32x4* o = fr == 0 ? oA : oB;
    const float ss = fr == 0 ? ssA : ssB;
    const float lse = M0_ + __logf(ss);
    const float inv = 1.f / ss;
    float* tp;
    float* lp;
    if (outmode == 0) {
      const int trow = chunkc * 1016 + qrow;
      tp = tail_attn + ((size_t)h * NT_ + trow) * 64;
      lp = tail_lse + h * NT_ + trow;
    } else if (outmode == 1) {
      tp = attn2 + ((size_t)(p2slot + qrow)) * 64;
      lp = lse2 + p2slot + qrow;
    } else {
      const int trow = chunkc * 1016 + qrow;
      tp = attn4 + ((size_t)h * NT_ + trow) * 64;
      lp = lse4 + h * NT_ + trow;
    }
    *(f32x4*)(tp +  0 + 4*g) = o[0] * inv;
    *(f32x4*)(tp + 16 + 4*g) = o[1] * inv;
    *(f32x4*)(tp + 32 + 4*g) = o[2] * inv;
    *(f32x4*)(tp + 48 + 4*g) = o[3] * inv;
    if (lane < 16) *lp = lse;
  }
}

// =========================================================================
// MFMA LSH attention, split per reference: grid 512.
// =========================================================================
__global__ __launch_bounds__(256) void kern_lsh_mfma(
    const float* __restrict__ Q, const ushort* __restrict__ Kb, const ushort* __restrict__ Vb,
    const int* __restrict__ q_sort, const int* __restrict__ k_sort,
    const int* __restrict__ samp_pos, const int* __restrict__ samp_orig,
    float* __restrict__ attn3, float* __restrict__ lse3) {
  __shared__ uint kk[2304];
  __shared__ uint vv[2304];
  __shared__ uint pbuf[1280];
  __shared__ float bias_s[64];

  const int b = blockIdx.x;
  const int which = b >> 8;            // 0 = diag, 1 = sampled
  const int bq = b & 255;
  const int h = bq >> 4, pt = bq & 15;
  const int tid = threadIdx.x;
  const int lane = tid & 63, w = tid >> 6;
  const int g = lane >> 4, q = lane & 15;
  const int blkq = pt >> 1;
  const size_t hN = (size_t)h * N_;

  const int pA = pt * 128 + w * 16 + q;
  const int pB = pA + 64;
  const int qiA = q_sort[h * NL_ + min(pA, NL_ - 1)];
  const int qiB = q_sort[h * NL_ + min(pB, NL_ - 1)];

  const int skey = tid >> 2, kpart = tid & 3;
  const int kpi = tid & 31, vdb = (tid >> 5) * 8;
  int kidx[4], vi0[4], vi1[4];
  float biasr[4];
#pragma unroll
  for (int t = 0; t < 4; ++t) {
    if (which == 0) {
      const int slot = blkq * 256 + t * 64 + skey;
      kidx[t] = (slot < NL_) ? k_sort[h * NL_ + slot] : -1;
      const int s0 = blkq * 256 + t * 64 + 2 * kpi;
      vi0[t] = (s0 < NL_) ? k_sort[h * NL_ + s0] : -1;
      vi1[t] = (s0 + 1 < NL_) ? k_sort[h * NL_ + s0 + 1] : -1;
    } else {
      kidx[t] = samp_orig[h * SAMP_ + t * 64 + skey];
      const int si = t * 64 + 2 * kpi;
      vi0[t] = samp_orig[h * SAMP_ + si];
      vi1[t] = samp_orig[h * SAMP_ + si + 1];
    }
  }
  if (which == 1 && tid < 64) {
#pragma unroll
    for (int j = 0; j < 4; ++j)
      biasr[j] = ((samp_pos[h * SAMP_ + j * 64 + tid] >> 8) == blkq) ? NEGBIG_ : LOGOFF_L2_;
  }

  B8 qbA0, qbA1, qbB0, qbB1;
  {
    const float4* qp = (const float4*)(Q + (hN + SINK_ + NL_ + qiA) * 64);
    float4 a = qp[2*g], c = qp[2*g+1], d = qp[8+2*g], e = qp[8+2*g+1];
    qbA0.u = make_uint4(bfpack(a.x*QSCALE_, a.y*QSCALE_), bfpack(a.z*QSCALE_, a.w*QSCALE_),
                        bfpack(c.x*QSCALE_, c.y*QSCALE_), bfpack(c.z*QSCALE_, c.w*QSCALE_));
    qbA1.u = make_uint4(bfpack(d.x*QSCALE_, d.y*QSCALE_), bfpack(d.z*QSCALE_, d.w*QSCALE_),
                        bfpack(e.x*QSCALE_, e.y*QSCALE_), bfpack(e.z*QSCALE_, e.w*QSCALE_));
    const float4* qp2 = (const float4*)(Q + (hN + SINK_ + NL_ + qiB) * 64);
    a = qp2[2*g]; c = qp2[2*g+1]; d = qp2[8+2*g]; e = qp2[8+2*g+1];
    qbB0.u = make_uint4(bfpack(a.x*QSCALE_, a.y*QSCALE_), bfpack(a.z*QSCALE_, a.w*QSCALE_),
                        bfpack(c.x*QSCALE_, c.y*QSCALE_), bfpack(c.z*QSCALE_, c.w*QSCALE_));
    qbB1.u = make_uint4(bfpack(d.x*QSCALE_, d.y*QSCALE_), bfpack(d.z*QSCALE_, d.w*QSCALE_),
                        bfpack(e.x*QSCALE_, e.y*QSCALE_), bfpack(e.z*QSCALE_, e.w*QSCALE_));
  }
  f32x4 oA[4] = {{0,0,0,0},{0,0,0,0},{0,0,0,0},{0,0,0,0}};
  f32x4 oB[4] = {{0,0,0,0},{0,0,0,0},{0,0,0,0},{0,0,0,0}};
  float ssA = 0.f, ssB = 0.f;
  const f32x4 accb = {-M0L2_, -M0L2_, -M0L2_, -M0L2_};

  char* kdst = (char*)kk + skey * 144 + kpart * 32;
  char* vdst = (char*)vv + vdb * 144 + kpi * 4;
  const char* kq = (const char*)kk + q * 144 + g * 16;
  const char* vq = (const char*)vv + q * 144 + g * 16;
  char* pw = (char*)pbuf + w * 1280 + q * 80;

  const uint4 z4 = make_uint4(0, 0, 0, 0);
  uint4 kp0, kp1, va, vb_;

#define LLOADK(T) { const int kr = kidx[T]; \
    if (kr >= 0) { const uint4* s = (const uint4*)(Kb + (hN + SINK_ + kr) * 64 + kpart * 16); \
      kp0 = s[0]; kp1 = s[1]; } else { kp0 = z4; kp1 = z4; } }
#define LLOADV(T) { const int r0 = vi0[T], r1 = vi1[T]; \
    va  = (r0 >= 0) ? *(const uint4*)(Vb + (hN + SINK_ + r0) * 64 + vdb) : z4; \
    vb_ = (r1 >= 0) ? *(const uint4*)(Vb + (hN + SINK_ + r1) * 64 + vdb) : z4; }

  LLOADK(0) LLOADV(0)

  for (int t = 0; t < 4; ++t) {
    __syncthreads();
    *(uint4*)kdst = kp0; *(uint4*)(kdst + 16) = kp1;
#define VP(JW, AW, BW) { \
    *(uint*)(vdst + (2*(JW)) * 144) = (AW & 0xffffu) | (BW << 16); \
    *(uint*)(vdst + (2*(JW) + 1) * 144) = (AW >> 16) | (BW & 0xffff0000u); }
    VP(0, va.x, vb_.x) VP(1, va.y, vb_.y) VP(2, va.z, vb_.z) VP(3, va.w, vb_.w)
#undef VP
    if (which == 1 && tid < 64) bias_s[tid] = biasr[t];
    __syncthreads();
    if (t + 1 < 4) { LLOADK(t + 1) LLOADV(t + 1) }

    f32x4 sA[4], sB[4];
    __builtin_amdgcn_s_setprio(1);
#pragma unroll
    for (int st = 0; st < 4; ++st) {
      B8 ka, kb2;
      ka.u  = *(const uint4*)(kq + (st * 16) * 144);
      kb2.u = *(const uint4*)(kq + (st * 16) * 144 + 64);
      f32x4 acc = accb;
      acc = mfma16(ka, qbA0, acc); acc = mfma16(kb2, qbA1, acc);
      sA[st] = acc;
      f32x4 acc2 = accb;
      acc2 = mfma16(ka, qbB0, acc2); acc2 = mfma16(kb2, qbB1, acc2);
      sB[st] = acc2;
    }
    __builtin_amdgcn_s_setprio(0);
    if (which == 1) {
      const f32x4* bp = (const f32x4*)bias_s;
#pragma unroll
      for (int st = 0; st < 4; ++st) {
        sA[st] = sA[st] + bp[st * 4 + g];
        sB[st] = sB[st] + bp[st * 4 + g];
      }
    }

    nomax_sm(sA, ssA);
    pv144(sA, oA, vq, pw, g);
    nomax_sm(sB, ssB);
    pv144(sB, oB, vq, pw, g);
  }
#undef LLOADK
#undef LLOADV

  ssA += __shfl_xor(ssA, 16); ssA += __shfl_xor(ssA, 32);
  ssB += __shfl_xor(ssB, 16); ssB += __shfl_xor(ssB, 32);
  const size_t obase = (size_t)which * 16 * NL_;
#pragma unroll
  for (int fr = 0; fr < 2; ++fr) {
    const int p = fr == 0 ? pA : pB;
    if (p >= NL_) continue;
    const int qi = fr == 0 ? qiA : qiB;
    f32x4* o = fr == 0 ? oA : oB;
    const float ss = fr == 0 ? ssA : ssB;
    const float un = M0_ + __logf(ss);
    const float inv = 1.f / ss;
    float* tp = attn3 + (obase + (size_t)h * NL_ + qi) * 64;
    *(f32x4*)(tp +  0 + 4*g) = o[0] * inv;
    *(f32x4*)(tp + 16 + 4*g) = o[1] * inv;
    *(f32x4*)(tp + 32 + 4*g) = o[2] * inv;
    *(f32x4*)(tp + 48 + 4*g) = o[3] * inv;
    if (lane < 16) lse3[obase + h * NL_ + qi] = un;
  }
}

// ---------------- sink prefix (no-max, ILP) + full ordered merge ----------------
__global__ __launch_bounds__(256) void kern_final(
    const float* __restrict__ Q, const float* __restrict__ K, const float* __restrict__ V,
    const float* __restrict__ tail_attn, const float* __restrict__ tail_lse,
    const float* __restrict__ attn2, const float* __restrict__ lse2,
    const float* __restrict__ attn3, const float* __restrict__ lse3,
    const float* __restrict__ attn4, const float* __restrict__ lse4,
    float* __restrict__ out) {
  const int h = blockIdx.x;
  const int r = blockIdx.y * 256 + (int)threadIdx.x;

  __shared__ float4 kk[SINK_ * 16];
  __shared__ float4 vv[SINK_ * 16];
  for (int u = threadIdx.x; u < SINK_ * 16; u += 256) {
    const int row = u >> 4, d4 = u & 15;
    kk[u] = ((const float4*)(K + ((size_t)h * N_ + row) * 64))[d4];
    vv[u] = ((const float4*)(V + ((size_t)h * N_ + row) * 64))[d4];
  }
  __syncthreads();

  float4 q4[16], acc[16];
  const float4* qp = (const float4*)(Q + ((size_t)h * N_ + r) * 64);
#pragma unroll
  for (int d = 0; d < 16; ++d) { q4[d] = qp[d]; acc[d] = make_float4(0.f, 0.f, 0.f, 0.f); }

  float ssum = 0.f;
  const int nk = min(SINK_, r + 1);
  for (int j = 0; j < nk; ++j) {
    float s = 0.f;
#pragma unroll
    for (int d = 0; d < 16; ++d) {
      float4 x = q4[d], y = kk[j * 16 + d];
      s = fmaf(x.x, y.x, s); s = fmaf(x.y, y.y, s);
      s = fmaf(x.z, y.z, s); s = fmaf(x.w, y.w, s);
    }
    const float wgt = __expf(fmaf(s, SCALE_, -M0_));
    ssum += wgt;
    const float4* v4 = &vv[j * 16];
#pragma unroll
    for (int d = 0; d < 16; ++d) {
      acc[d].x = fmaf(wgt, v4[d].x, acc[d].x);
      acc[d].y = fmaf(wgt, v4[d].y, acc[d].y);
      acc[d].z = fmaf(wgt, v4[d].z, acc[d].z);
      acc[d].w = fmaf(wgt, v4[d].w, acc[d].w);
    }
  }
  const float pl = M0_ + __logf(ssum);
  const float inv = 1.f / ssum;
  float4* op = (float4*)(out + ((size_t)h * N_ + r) * 64);
  if (r < SINK_) {
#pragma unroll
    for (int d = 0; d < 16; ++d)
      op[d] = make_float4(acc[d].x * inv, acc[d].y * inv, acc[d].z * inv, acc[d].w * inv);
    return;
  }

  const int t = r - SINK_;
  float4 a[16];
  const float4* tp = (const float4*)(tail_attn + ((size_t)h * NT_ + t) * 64);
#pragma unroll
  for (int d = 0; d < 16; ++d) a[d] = tp[d];
  float al = tail_lse[h * NT_ + t];

  const int chunk = t / 1016;
  const int qrow = t - chunk * 1016;
  if (qrow >= 512) {    // combine P1 split-K halves (exact)
    const float l4 = lse4[h * NT_ + t];
    const float c = 1.f / (1.f + __expf(l4 - al));
    const float4* bp = (const float4*)(attn4 + ((size_t)h * NT_ + t) * 64);
#pragma unroll
    for (int d = 0; d < 16; ++d) {
      const float4 bb = bp[d];
      a[d] = make_float4(c * a[d].x + (1.f - c) * bb.x,
                         c * a[d].y + (1.f - c) * bb.y,
                         c * a[d].z + (1.f - c) * bb.z,
                         c * a[d].w + (1.f - c) * bb.w);
    }
    al = logaddexpf_(al, l4);
  }

  const int pp = (t >= NL_) ? 1 : 0;
  const int tloc = t - pp * NL_;
  if (tloc >= 1016) {   // P2 merge (split-K halves combined exactly, then into P1)
    const int vh = h * 2 + pp, i = tloc - 1016;
    const float l20 = lse2[vh * 1016 + i];
    const float l21 = lse2[32 * 1016 + vh * 1016 + i];
    const float c12 = 1.f / (1.f + __expf(l21 - l20));
    const float l2 = logaddexpf_(l20, l21);
    const float c = 1.f / (1.f + __expf(l2 - al));
    const float4* b0 = (const float4*)(attn2 + ((size_t)(vh * 1016 + i)) * 64);
    const float4* b1 = (const float4*)(attn2 + ((size_t)(32 * 1016 + vh * 1016 + i)) * 64);
#pragma unroll
    for (int d = 0; d < 16; ++d) {
      const float4 x0 = b0[d], x1 = b1[d];
      const float4 bb = make_float4(c12 * x0.x + (1.f - c12) * x1.x,
                                    c12 * x0.y + (1.f - c12) * x1.y,
                                    c12 * x0.z + (1.f - c12) * x1.z,
                                    c12 * x0.w + (1.f - c12) * x1.w);
      a[d] = make_float4(c * a[d].x + (1.f - c) * bb.x,
                         c * a[d].y + (1.f - c) * bb.y,
                         c * a[d].z + (1.f - c) * bb.z,
                         c * a[d].w + (1.f - c) * bb.w);
    }
    al = logaddexpf_(al, l2);
  }
  if (t >= NL_) {       // LSH merge: add_self(block, res), then into tail
    const int qi = t - NL_;
    const float l3a = lse3[h * NL_ + qi];
    const float l3b = lse3[16 * NL_ + h * NL_ + qi];
    const float c34 = 1.f / (1.f + __expf(l3b - l3a));
    const float l3 = logaddexpf_(l3a, l3b);
    const float c = 1.f / (1.f + __expf(l3 - al));
    const float4* b0 = (const float4*)(attn3 + ((size_t)(h * NL_ + qi)) * 64);
    const float4* b1 = (const float4*)(attn3 + ((size_t)(16 * NL_ + h * NL_ + qi)) * 64);
#pragma unroll
    for (int d = 0; d < 16; ++d) {
      const float4 x0 = b0[d], x1 = b1[d];
      const float4 bb = make_float4(c34 * x0.x + (1.f - c34) * x1.x,
                                    c34 * x0.y + (1.f - c34) * x1.y,
                                    c34 * x0.z + (1.f - c34) * x1.z,
                                    c34 * x0.w + (1.f - c34) * x1.w);
      a[d] = make_float4(c * a[d].x + (1.f - c) * bb.x,
                         c * a[d].y + (1.f - c) * bb.y,
                         c * a[d].z + (1.f - c) * bb.z,
                         c * a[d].w + (1.f - c) * bb.w);
    }
    al = logaddexpf_(al, l3);
  }
  const float cc = 1.f / (1.f + __expf(al - pl));
#pragma unroll
  for (int d = 0; d < 16; ++d)
    op[d] = make_float4(cc * acc[d].x * inv + (1.f - cc) * a[d].x,
                        cc * acc[d].y * inv + (1.f - cc) * a[d].y,
                        cc * acc[d].z * inv + (1.f - cc) * a[d].z,
                        cc * acc[d].w * inv + (1.f - cc) * a[d].w);
}

// ---------------- host ----------------
extern "C" void kernel_launch(void* const* d_in, const int* in_sizes, int n_in,
                              void* d_out, int out_size, void* d_ws, size_t ws_size,
                              hipStream_t stream) {
  (void)in_sizes; (void)n_in; (void)out_size; (void)ws_size;
  const float* Q = (const float*)d_in[0];
  const float* K = (const float*)d_in[1];
  const float* V = (const float*)d_in[2];
  const float* proj = (const float*)d_in[3];
  float* out = (float*)d_out;

  char* w = (char*)d_ws;
  auto carve = [&](size_t bytes) { char* p = w; w += (bytes + 255) & ~(size_t)255; return p; };
  float* tail_attn = (float*)carve((size_t)H_ * NT_ * 64 * sizeof(float));
  float* tail_lse  = (float*)carve((size_t)H_ * NT_ * sizeof(float));
  float* attn2     = (float*)carve((size_t)2 * 32 * 1016 * 64 * sizeof(float));
  float* lse2      = (float*)carve((size_t)2 * 32 * 1016 * sizeof(float));
  float* attn3     = (float*)carve((size_t)2 * H_ * NL_ * 64 * sizeof(float));
  float* lse3      = (float*)carve((size_t)2 * H_ * NL_ * sizeof(float));
  float* attn4     = (float*)carve((size_t)H_ * NT_ * 64 * sizeof(float));
  float* lse4      = (float*)carve((size_t)H_ * NT_ * sizeof(float));
  ushort* Kb     = (ushort*)carve((size_t)H_ * N_ * 64 * sizeof(ushort));
  ushort* Vb     = (ushort*)carve((size_t)H_ * N_ * 64 * sizeof(ushort));
  ushort* Vt     = (ushort*)carve((size_t)H_ * N_ * 64 * sizeof(ushort) + 4096);
  int* hq        = (int*)carve((size_t)H_ * NL_ * sizeof(int));
  int* hk        = (int*)carve((size_t)H_ * NL_ * sizeof(int));
  int* q_sort    = (int*)carve((size_t)H_ * NL_ * sizeof(int));
  int* k_sort    = (int*)carve((size_t)H_ * NL_ * sizeof(int));
  int* samp_pos  = (int*)carve((size_t)H_ * SAMP_ * sizeof(int));
  int* samp_orig = (int*)carve((size_t)H_ * SAMP_ * sizeof(int));

  kern_packhash<<<dim3(3328), 256, 0, stream>>>(K, V, Q, proj, Kb, Vb, Vt, hq, hk);
  kern_sortsamp<<<dim3(H_, 2), 256, 0, stream>>>(hq, hk, q_sort, k_sort, samp_pos, samp_orig);
  kern_attn_mfma<<<dim3(1280), 256, 0, stream>>>(Q, Kb, Vt, tail_attn, tail_lse,
                                                 attn2, lse2, attn4, lse4);
  kern_lsh_mfma<<<dim3(512), 256, 0, stream>>>(Q, Kb, Vb, q_sort, k_sort, samp_pos, samp_orig,
                                               attn3, lse3);
  kern_final<<<dim3(H_, 16), 256, 0, stream>>>(Q, K, V, tail_attn, tail_lse,
                                               attn2, lse2, attn3, lse3, attn4, lse4, out);
}

// Round 13
// 128.389 us; speedup vs baseline: 1.0754x; 1.0754x over previous
//
#include <hip/hip_runtime.h>
#include <hip/hip_bf16.h>
#include <math.h>
#include <stdint.h>

#define H_ 16
#define N_ 4096
#define NT_ 4064        // tail length
#define NL_ 2032        // LSH segment length
#define SINK_ 32
#define SAMP_ 256
#define SCALE_ 0.125f
#define QSCALE_ 0.18033688f    // 0.125 * log2(e)
#define M0L2_ 11.5415606f      // 8 * log2(e)
#define M0_ 8.0f
#define NEGBIG_ -3.0e38f
#define LOGOFF_L2_ 2.9886841f  // log2(2032/256)

typedef unsigned int uint;
typedef unsigned short ushort;
typedef short bf16x8 __attribute__((ext_vector_type(8)));
typedef float f32x4 __attribute__((ext_vector_type(4)));

union B8 { uint4 u; bf16x8 b; };

__device__ __forceinline__ f32x4 mfma16(const B8& a, const B8& b, f32x4 c) {
  return __builtin_amdgcn_mfma_f32_16x16x32_bf16(a.b, b.b, c, 0, 0, 0);
}

__device__ __forceinline__ uint bfpack(float a, float b) {
  uint ua = __float_as_uint(a), ub = __float_as_uint(b);
  ua += 0x7fffu + ((ua >> 16) & 1u);
  ub += 0x7fffu + ((ub >> 16) & 1u);
  return (ua >> 16) | (ub & 0xffff0000u);
}

__device__ __forceinline__ uint cvtpk(float a, float b) {
  union { __hip_bfloat162 h; uint u; } r;
  r.h.x = __float2bfloat16(a);
  r.h.y = __float2bfloat16(b);
  return r.u;
}

__device__ __forceinline__ float bl_(uint u) { return __uint_as_float(u << 16); }
__device__ __forceinline__ float bh_(uint u) { return __uint_as_float(u & 0xffff0000u); }

__device__ __forceinline__ float logaddexpf_(float a, float b) {
  float mx = fmaxf(a, b);
  return mx + __logf(__expf(a - mx) + __expf(b - mx));
}

__device__ __forceinline__ uint32_t rotl32_(uint32_t v, uint32_t d) {
  return (v << d) | (v >> (32u - d));
}

// JAX threefry2x32 (20 rounds)
__device__ inline void tf2x32(uint32_t k0, uint32_t k1, uint32_t& x0, uint32_t& x1) {
  uint32_t ks2 = k0 ^ k1 ^ 0x1BD11BDAu;
  x0 += k0; x1 += k1;
#define TFR(r) { x0 += x1; x1 = rotl32_(x1, r); x1 ^= x0; }
  TFR(13u) TFR(15u) TFR(26u) TFR(6u)
  x0 += k1;  x1 += ks2 + 1u;
  TFR(17u) TFR(29u) TFR(16u) TFR(24u)
  x0 += ks2; x1 += k0 + 2u;
  TFR(13u) TFR(15u) TFR(26u) TFR(6u)
  x0 += k0;  x1 += k1 + 3u;
  TFR(17u) TFR(29u) TFR(16u) TFR(24u)
  x0 += k1;  x1 += ks2 + 4u;
  TFR(13u) TFR(15u) TFR(26u) TFR(6u)
  x0 += ks2; x1 += k0 + 5u;
#undef TFR
}

// ---------------- fixed-offset softmax ----------------
__device__ __forceinline__ void nomax_sm(f32x4 s[4], float& ssum) {
#pragma unroll
  for (int st = 0; st < 4; ++st)
#pragma unroll
    for (int r = 0; r < 4; ++r) {
      s[st][r] = __builtin_exp2f(s[st][r]);
      ssum += s[st][r];
    }
}

// ---------------- PV (lsh layout): vv rows stride 144, linear pbuf ----------------
__device__ __forceinline__ void pv144(const f32x4 s[4], f32x4 o[4],
                                      const char* vbase, char* pw, int g) {
  __builtin_amdgcn_s_setprio(1);
#pragma unroll
  for (int hk2 = 0; hk2 < 2; ++hk2) {
    const f32x4 pa = s[2 * hk2], pc = s[2 * hk2 + 1];
    *(uint2*)(pw + 8 * g)      = make_uint2(cvtpk(pa[0], pa[1]), cvtpk(pa[2], pa[3]));
    *(uint2*)(pw + 32 + 8 * g) = make_uint2(cvtpk(pc[0], pc[1]), cvtpk(pc[2], pc[3]));
    B8 pf, vf;
    pf.u = *(const uint4*)(pw + g * 16);
    vf.u = *(const uint4*)(vbase + 0 * 2304 + hk2 * 64); o[0] = mfma16(vf, pf, o[0]);
    vf.u = *(const uint4*)(vbase + 1 * 2304 + hk2 * 64); o[1] = mfma16(vf, pf, o[1]);
    vf.u = *(const uint4*)(vbase + 2 * 2304 + hk2 * 64); o[2] = mfma16(vf, pf, o[2]);
    vf.u = *(const uint4*)(vbase + 3 * 2304 + hk2 * 64); o[3] = mfma16(vf, pf, o[3]);
  }
  __builtin_amdgcn_s_setprio(0);
}

// bf16 epilogue store: o[0..3]*inv -> 4 x uint2 at ushort offsets {0,16,32,48}+4g
__device__ __forceinline__ void store_o_bf16(ushort* tp, const f32x4 o[4], float inv, int g) {
#pragma unroll
  for (int d = 0; d < 4; ++d) {
    const f32x4 r = o[d] * inv;
    *(uint2*)(tp + d * 16 + 4 * g) = make_uint2(cvtpk(r[0], r[1]), cvtpk(r[2], r[3]));
  }
}

// =========================================================================
// pack: blocks 0..2047 K bf16 linear; 2048..3071 V transpose; 3072..3327 hash.
// =========================================================================
__global__ __launch_bounds__(256) void kern_packhash(
    const float* __restrict__ K, const float* __restrict__ V, const float* __restrict__ Q,
    const float* __restrict__ proj,
    ushort* __restrict__ Kb, ushort* __restrict__ Vb, ushort* __restrict__ Vt,
    int* __restrict__ hq, int* __restrict__ hk) {
  const int bb = blockIdx.x;
  const int tid = threadIdx.x;
  if (bb < 2048) {               // ---- K linear pack ----
    const size_t idx = (size_t)bb * 256 + tid;
    const float4* s = (const float4*)(K + idx * 8);
    float4 f0 = s[0], f1 = s[1];
    uint4 p = make_uint4(bfpack(f0.x, f0.y), bfpack(f0.z, f0.w),
                         bfpack(f1.x, f1.y), bfpack(f1.z, f1.w));
    *(uint4*)(Kb + idx * 8) = p;
    return;
  }
  if (bb < 3072) {               // ---- V transpose + row pack ----
    __shared__ ushort tr[64 * 72];
    const int u = bb - 2048;
    const int h = u >> 6, nt = u & 63;
    const int n0 = nt * 64;
    const size_t hN = (size_t)h * N_;
    const int nloc = tid >> 2, dpart = (tid & 3) * 16;
    const float4* src = (const float4*)(V + (hN + n0 + nloc) * 64 + dpart);
    float4 f0 = src[0], f1 = src[1], f2 = src[2], f3 = src[3];
    uint p0 = bfpack(f0.x, f0.y), p1 = bfpack(f0.z, f0.w);
    uint p2 = bfpack(f1.x, f1.y), p3 = bfpack(f1.z, f1.w);
    uint p4 = bfpack(f2.x, f2.y), p5 = bfpack(f2.z, f2.w);
    uint p6 = bfpack(f3.x, f3.y), p7 = bfpack(f3.z, f3.w);
    ushort* vbdst = Vb + (hN + n0 + nloc) * 64 + dpart;
    ((uint4*)vbdst)[0] = make_uint4(p0, p1, p2, p3);
    ((uint4*)vbdst)[1] = make_uint4(p4, p5, p6, p7);
    uint pv[8] = {p0, p1, p2, p3, p4, p5, p6, p7};
#pragma unroll
    for (int j = 0; j < 8; ++j) {
      tr[(dpart + 2 * j    ) * 72 + nloc] = (ushort)(pv[j] & 0xffffu);
      tr[(dpart + 2 * j + 1) * 72 + nloc] = (ushort)(pv[j] >> 16);
    }
    __syncthreads();
    const int d = tid >> 2, np = (tid & 3) * 16;
    const uint4* tp = (const uint4*)(tr + d * 72 + np);
    uint4 t0 = tp[0], t1 = tp[1];
    ushort* dst = Vt + ((size_t)(h * 64 + d)) * 4096 + n0 + np;
    ((uint4*)dst)[0] = t0;
    ((uint4*)dst)[1] = t1;
    return;
  }
  // ---- hash ----
  __shared__ float pr[448];
  const int u = bb - 3072;
  const int h = u & 15, tile = (u >> 4) & 7, which = u >> 7;
  for (int t = tid; t < 448; t += 256) pr[t] = proj[t];
  __syncthreads();
  const int i = tile * 256 + tid;
  if (i >= NL_) return;
  const int orig = (which == 0) ? (SINK_ + NL_ + i) : (SINK_ + i);
  const float4* x = (const float4*)((which == 0 ? Q : K) + ((size_t)h * N_ + orig) * 64);
  float xr[64];
#pragma unroll
  for (int d = 0; d < 16; ++d) {
    float4 g = x[d];
    xr[4*d+0] = g.x; xr[4*d+1] = g.y; xr[4*d+2] = g.z; xr[4*d+3] = g.w;
  }
  int bin = 0;
#pragma unroll
  for (int r = 0; r < 7; ++r) {
    float acc = 0.f;
#pragma unroll
    for (int d = 0; d < 64; ++d) acc = fmaf(xr[d], pr[d * 7 + r], acc);
    if (acc > 0.f) bin |= (1 << r);
  }
  const int g = bin ^ (bin >> 1);
  (which == 0 ? hq : hk)[h * NL_ + i] = g;
}

// ---------------- chunked stable counting sort + threefry sample ----------------
__global__ __launch_bounds__(256) void kern_sortsamp(
    const int* __restrict__ hq, const int* __restrict__ hk,
    int* __restrict__ q_sort, int* __restrict__ k_sort,
    int* __restrict__ samp_pos, int* __restrict__ samp_orig) {
  const int h = blockIdx.x, which = blockIdx.y;
  const int tid = threadIdx.x;

  __shared__ unsigned char keys8[NL_];
  __shared__ ushort M[64 * 130];
  __shared__ int btot[128];
  __shared__ int bscan[128];
  __shared__ ushort srt[NL_];

  const int* src = (which == 0 ? hq : hk) + h * NL_;
  for (int u = tid; u < 64 * 130 / 2; u += 256) ((uint*)M)[u] = 0u;
  for (int u = tid; u < NL_; u += 256) keys8[u] = (unsigned char)src[u];
  __syncthreads();

  if (tid < 64) {
    const int c = tid;
#pragma unroll 4
    for (int j = 0; j < 32; ++j) {
      const int u = c * 32 + j;
      if (u < NL_) ++M[c * 130 + keys8[u]];
    }
  }
  __syncthreads();

  if (tid < 128) {
    const int b = tid;
    int run = 0;
    for (int c = 0; c < 64; ++c) {
      const int v = M[c * 130 + b];
      M[c * 130 + b] = (ushort)run;
      run += v;
    }
    btot[b] = run;
    bscan[b] = run;
  }
  __syncthreads();

  for (int ofs = 1; ofs < 128; ofs <<= 1) {
    int v = 0;
    if (tid < 128 && tid >= ofs) v = bscan[tid - ofs];
    __syncthreads();
    if (tid < 128) bscan[tid] += v;
    __syncthreads();
  }

  int* dst = (which == 0 ? q_sort : k_sort) + h * NL_;
  if (tid < 64) {
    const int c = tid;
    for (int j = 0; j < 32; ++j) {
      const int u = c * 32 + j;
      if (u < NL_) {
        const int k = keys8[u];
        const int pos = (bscan[k] - btot[k]) + M[c * 130 + k];
        M[c * 130 + k] += 1;
        dst[pos] = u;
        srt[pos] = (ushort)u;
      }
    }
  }
  __syncthreads();

  if (which == 1) {
    const int s = tid;
    uint32_t a0 = 0u, a1 = 0u; tf2x32(0u, 1234u, a0, a1);
    uint32_t b0 = 0u, b1 = 0u; tf2x32(a0, a1, b0, b1);
    uint32_t c0 = 0u, c1 = 1u; tf2x32(a0, a1, c0, c1);
    const uint32_t j = (uint32_t)(h * SAMP_ + s);
    uint32_t h0 = 0u, h1 = j; tf2x32(b0, b1, h0, h1);
    uint32_t l0 = 0u, l1 = j; tf2x32(c0, c1, l0, l1);
    const uint32_t Hb = h0 ^ h1, Lb = l0 ^ l1;
    const uint32_t off = ((Hb % 2032u) * 16u + (Lb % 2032u)) % 2032u;
    samp_pos[h * SAMP_ + s] = (int)off;
    samp_orig[h * SAMP_ + s] = (int)srt[off];
  }
}

// =========================================================================
// MFMA flash attention (R11 structure). Grid 1024:
//   blocks 0..511  : P1 causal (LPT desc qt), 1..8 tiles -> tailb (bf16).
//   blocks 512..1023: P2 split-K halves, 4 tiles -> attn2b (bf16).
// =========================================================================
__global__ __launch_bounds__(256) void kern_attn_mfma(
    const float* __restrict__ Q, const ushort* __restrict__ Kb, const ushort* __restrict__ Vt,
    ushort* __restrict__ tailb, float* __restrict__ tail_lse,
    ushort* __restrict__ attn2b, float* __restrict__ lse2) {
  __shared__ uint kk[4608];
  __shared__ uint vv[4352];
  __shared__ uint pbuf[1280];

  const int b = blockIdx.x;
  const int tid = threadIdx.x;
  const int lane = tid & 63, w = tid >> 6;
  const int g = lane >> 4, q = lane & 15;
  const uint4 z4 = make_uint4(0, 0, 0, 0);
  const f32x4 accb = {-M0L2_, -M0L2_, -M0L2_, -M0L2_};

  int h, q0, qbase, kbase, ntiles, klen, p2slot = 0, chunkc = 0;
  bool causal;
  if (b < 512) {                       // P1: LPT descending qt
    const int u = b; const int vh = u & 63;
    const int qt = 7 - (u >> 6);
    h = vh >> 2; chunkc = vh & 3;
    q0 = qt * 128;
    qbase = SINK_ + chunkc * 1016;
    kbase = qbase;
    ntiles = qt + 1; causal = true; klen = 1016;
  } else {                             // P2 split-K halves
    const int u = b - 512; const int vh = u & 31; const int qt = (u >> 5) & 7;
    const int hf = u >> 8;
    h = vh >> 1; const int pp = vh & 1;
    q0 = qt * 128;
    qbase = SINK_ + pp * 2032 + 1016;
    kbase = SINK_ + pp * 2032 + hf * 512;
    ntiles = 4; causal = false; klen = hf ? 504 : 512;
    p2slot = hf * 32 * 1016 + vh * 1016;
  }
  const size_t hN = (size_t)h * N_;
  const int qrowA = q0 + w * 16 + q;
  const int qrowB = qrowA + 64;
  const int qcA = min(qrowA, 1015), qcB = min(qrowB, 1015);
  const int qwA_lo = q0 + w * 16, qwmaxA = qwA_lo + 15;
  const int qwB_lo = qwA_lo + 64;

  B8 qbA0, qbA1, qbB0, qbB1;
  {
    const float4* qp = (const float4*)(Q + (hN + qbase + qcA) * 64);
    float4 a = qp[2*g], c = qp[2*g+1], d = qp[8+2*g], e = qp[8+2*g+1];
    qbA0.u = make_uint4(bfpack(a.x*QSCALE_, a.y*QSCALE_), bfpack(a.z*QSCALE_, a.w*QSCALE_),
                        bfpack(c.x*QSCALE_, c.y*QSCALE_), bfpack(c.z*QSCALE_, c.w*QSCALE_));
    qbA1.u = make_uint4(bfpack(d.x*QSCALE_, d.y*QSCALE_), bfpack(d.z*QSCALE_, d.w*QSCALE_),
                        bfpack(e.x*QSCALE_, e.y*QSCALE_), bfpack(e.z*QSCALE_, e.w*QSCALE_));
    const float4* qp2 = (const float4*)(Q + (hN + qbase + qcB) * 64);
    a = qp2[2*g]; c = qp2[2*g+1]; d = qp2[8+2*g]; e = qp2[8+2*g+1];
    qbB0.u = make_uint4(bfpack(a.x*QSCALE_, a.y*QSCALE_), bfpack(a.z*QSCALE_, a.w*QSCALE_),
                        bfpack(c.x*QSCALE_, c.y*QSCALE_), bfpack(c.z*QSCALE_, c.w*QSCALE_));
    qbB1.u = make_uint4(bfpack(d.x*QSCALE_, d.y*QSCALE_), bfpack(d.z*QSCALE_, d.w*QSCALE_),
                        bfpack(e.x*QSCALE_, e.y*QSCALE_), bfpack(e.z*QSCALE_, e.w*QSCALE_));
  }
  f32x4 oA[4] = {{0,0,0,0},{0,0,0,0},{0,0,0,0},{0,0,0,0}};
  f32x4 oB[4] = {{0,0,0,0},{0,0,0,0},{0,0,0,0},{0,0,0,0}};
  float ssA = 0.f, ssB = 0.f;

  const int krow_l = tid >> 1, kpart = tid & 1;
  const int vrow = tid >> 2, vc32 = tid & 3;
  char* kdst = (char*)kk + krow_l * 144 + kpart * 64;
  char* vdst = (char*)vv + vrow * 272 + vc32 * 64;
  const char* kq = (const char*)kk + q * 144 + g * 16;
  const char* vq = (const char*)vv + q * 272 + g * 16;
  char* pw = (char*)pbuf + w * 1280 + q * 80;
  const size_t vtbase = ((size_t)(h * 64 + vrow)) * 4096 + kbase + vc32 * 32;

  uint4 kp0, kp1, kp2, kp3, va, va2, vb_, vb2;

#define LOADK(T) { const int kr = (T) * 128 + krow_l; \
    if (kr < klen) { const uint4* s = (const uint4*)(Kb + (hN + kbase + kr) * 64 + kpart * 32); \
      kp0 = s[0]; kp1 = s[1]; kp2 = s[2]; kp3 = s[3]; } \
    else { kp0 = z4; kp1 = z4; kp2 = z4; kp3 = z4; } }
#define LOADV(T) { const uint4* sv = (const uint4*)(Vt + vtbase + (size_t)(T) * 128); \
    va = sv[0]; va2 = sv[1]; vb_ = sv[2]; vb2 = sv[3]; }

  LOADK(0) LOADV(0)

  for (int t = 0; t < ntiles; ++t) {
    const int kt = t * 128;
    __syncthreads();
    *(uint4*)kdst = kp0; *(uint4*)(kdst + 16) = kp1;
    *(uint4*)(kdst + 32) = kp2; *(uint4*)(kdst + 48) = kp3;
    *(uint4*)vdst = va; *(uint4*)(vdst + 16) = va2;
    *(uint4*)(vdst + 32) = vb_; *(uint4*)(vdst + 48) = vb2;
    __syncthreads();
    if (t + 1 < ntiles) { LOADK(t + 1) LOADV(t + 1) }

#pragma unroll
    for (int u2 = 0; u2 < 2; ++u2) {
      const int hb = kt + u2 * 64;
      const bool dA = !(causal && hb > qwmaxA);
      f32x4 sA[4], sB[4];
      __builtin_amdgcn_s_setprio(1);
#pragma unroll
      for (int st = 0; st < 4; ++st) {
        B8 ka, kb2;
        ka.u  = *(const uint4*)(kq + (u2 * 64 + st * 16) * 144);
        kb2.u = *(const uint4*)(kq + (u2 * 64 + st * 16) * 144 + 64);
        if (dA) {
          f32x4 acc = accb;
          acc = mfma16(ka, qbA0, acc); acc = mfma16(kb2, qbA1, acc);
          sA[st] = acc;
        }
        f32x4 acc2 = accb;
        acc2 = mfma16(ka, qbB0, acc2); acc2 = mfma16(kb2, qbB1, acc2);
        sB[st] = acc2;
      }
      __builtin_amdgcn_s_setprio(0);

      if (causal) {
        const int kb0 = hb + 4 * g;
        if (dA && hb + 63 > qwA_lo) {
#pragma unroll
          for (int st = 0; st < 4; ++st)
#pragma unroll
            for (int r = 0; r < 4; ++r)
              if (kb0 + st * 16 + r > qrowA) sA[st][r] = NEGBIG_;
        }
        if (hb + 63 > qwB_lo) {
#pragma unroll
          for (int st = 0; st < 4; ++st)
#pragma unroll
            for (int r = 0; r < 4; ++r)
              if (kb0 + st * 16 + r > qrowB) sB[st][r] = NEGBIG_;
        }
      } else if (hb + 63 >= klen) {
        const int kb0 = hb + 4 * g;
#pragma unroll
        for (int st = 0; st < 4; ++st)
#pragma unroll
          for (int r = 0; r < 4; ++r)
            if (kb0 + st * 16 + r >= klen) { sA[st][r] = NEGBIG_; sB[st][r] = NEGBIG_; }
      }

#define PVX(SS, OO) { \
      __builtin_amdgcn_s_setprio(1); \
      _Pragma("unroll") \
      for (int hk2 = 0; hk2 < 2; ++hk2) { \
        const f32x4 pa = SS[2 * hk2], pc = SS[2 * hk2 + 1]; \
        *(uint2*)(pw + 8 * g)      = make_uint2(cvtpk(pa[0], pa[1]), cvtpk(pa[2], pa[3])); \
        *(uint2*)(pw + 32 + 8 * g) = make_uint2(cvtpk(pc[0], pc[1]), cvtpk(pc[2], pc[3])); \
        B8 pf, vf; \
        pf.u = *(const uint4*)(pw + g * 16); \
        const int vo = u2 * 128 + hk2 * 64; \
        vf.u = *(const uint4*)(vq + 0 * 4352 + vo); OO[0] = mfma16(vf, pf, OO[0]); \
        vf.u = *(const uint4*)(vq + 1 * 4352 + vo); OO[1] = mfma16(vf, pf, OO[1]); \
        vf.u = *(const uint4*)(vq + 2 * 4352 + vo); OO[2] = mfma16(vf, pf, OO[2]); \
        vf.u = *(const uint4*)(vq + 3 * 4352 + vo); OO[3] = mfma16(vf, pf, OO[3]); \
      } \
      __builtin_amdgcn_s_setprio(0); }

      if (dA) {
        nomax_sm(sA, ssA);
        PVX(sA, oA)
      }
      nomax_sm(sB, ssB);
      PVX(sB, oB)
#undef PVX
    }
  }
#undef LOADK
#undef LOADV

  ssA += __shfl_xor(ssA, 16); ssA += __shfl_xor(ssA, 32);
  ssB += __shfl_xor(ssB, 16); ssB += __shfl_xor(ssB, 32);
#pragma unroll
  for (int fr = 0; fr < 2; ++fr) {
    const int qrow = fr == 0 ? qrowA : qrowB;
    if (qrow >= 1016) continue;
    f32x4* o = fr == 0 ? oA : oB;
    const float ss = fr == 0 ? ssA : ssB;
    const float lse = M0_ + __logf(ss);
    const float inv = 1.f / ss;
    if (causal) {
      const int trow = chunkc * 1016 + qrow;
      store_o_bf16(tailb + ((size_t)h * NT_ + trow) * 64, o, inv, g);
      if (lane < 16) tail_lse[h * NT_ + trow] = lse;
    } else {
      store_o_bf16(attn2b + ((size_t)(p2slot + qrow)) * 64, o, inv, g);
      if (lane < 16) lse2[p2slot + qrow] = lse;
    }
  }
}

// =========================================================================
// MFMA LSH attention, split per reference: grid 512 -> attn3b (bf16).
// =========================================================================
__global__ __launch_bounds__(256) void kern_lsh_mfma(
    const float* __restrict__ Q, const ushort* __restrict__ Kb, const ushort* __restrict__ Vb,
    const int* __restrict__ q_sort, const int* __restrict__ k_sort,
    const int* __restrict__ samp_pos, const int* __restrict__ samp_orig,
    ushort* __restrict__ attn3b, float* __restrict__ lse3) {
  __shared__ uint kk[2304];
  __shared__ uint vv[2304];
  __shared__ uint pbuf[1280];
  __shared__ float bias_s[64];

  const int b = blockIdx.x;
  const int which = b >> 8;
  const int bq = b & 255;
  const int h = bq >> 4, pt = bq & 15;
  const int tid = threadIdx.x;
  const int lane = tid & 63, w = tid >> 6;
  const int g = lane >> 4, q = lane & 15;
  const int blkq = pt >> 1;
  const size_t hN = (size_t)h * N_;

  const int pA = pt * 128 + w * 16 + q;
  const int pB = pA + 64;
  const int qiA = q_sort[h * NL_ + min(pA, NL_ - 1)];
  const int qiB = q_sort[h * NL_ + min(pB, NL_ - 1)];

  const int skey = tid >> 2, kpart = tid & 3;
  const int kpi = tid & 31, vdb = (tid >> 5) * 8;
  int kidx[4], vi0[4], vi1[4];
  float biasr[4];
#pragma unroll
  for (int t = 0; t < 4; ++t) {
    if (which == 0) {
      const int slot = blkq * 256 + t * 64 + skey;
      kidx[t] = (slot < NL_) ? k_sort[h * NL_ + slot] : -1;
      const int s0 = blkq * 256 + t * 64 + 2 * kpi;
      vi0[t] = (s0 < NL_) ? k_sort[h * NL_ + s0] : -1;
      vi1[t] = (s0 + 1 < NL_) ? k_sort[h * NL_ + s0 + 1] : -1;
    } else {
      kidx[t] = samp_orig[h * SAMP_ + t * 64 + skey];
      const int si = t * 64 + 2 * kpi;
      vi0[t] = samp_orig[h * SAMP_ + si];
      vi1[t] = samp_orig[h * SAMP_ + si + 1];
    }
  }
  if (which == 1 && tid < 64) {
#pragma unroll
    for (int j = 0; j < 4; ++j)
      biasr[j] = ((samp_pos[h * SAMP_ + j * 64 + tid] >> 8) == blkq) ? NEGBIG_ : LOGOFF_L2_;
  }

  B8 qbA0, qbA1, qbB0, qbB1;
  {
    const float4* qp = (const float4*)(Q + (hN + SINK_ + NL_ + qiA) * 64);
    float4 a = qp[2*g], c = qp[2*g+1], d = qp[8+2*g], e = qp[8+2*g+1];
    qbA0.u = make_uint4(bfpack(a.x*QSCALE_, a.y*QSCALE_), bfpack(a.z*QSCALE_, a.w*QSCALE_),
                        bfpack(c.x*QSCALE_, c.y*QSCALE_), bfpack(c.z*QSCALE_, c.w*QSCALE_));
    qbA1.u = make_uint4(bfpack(d.x*QSCALE_, d.y*QSCALE_), bfpack(d.z*QSCALE_, d.w*QSCALE_),
                        bfpack(e.x*QSCALE_, e.y*QSCALE_), bfpack(e.z*QSCALE_, e.w*QSCALE_));
    const float4* qp2 = (const float4*)(Q + (hN + SINK_ + NL_ + qiB) * 64);
    a = qp2[2*g]; c = qp2[2*g+1]; d = qp2[8+2*g]; e = qp2[8+2*g+1];
    qbB0.u = make_uint4(bfpack(a.x*QSCALE_, a.y*QSCALE_), bfpack(a.z*QSCALE_, a.w*QSCALE_),
                        bfpack(c.x*QSCALE_, c.y*QSCALE_), bfpack(c.z*QSCALE_, c.w*QSCALE_));
    qbB1.u = make_uint4(bfpack(d.x*QSCALE_, d.y*QSCALE_), bfpack(d.z*QSCALE_, d.w*QSCALE_),
                        bfpack(e.x*QSCALE_, e.y*QSCALE_), bfpack(e.z*QSCALE_, e.w*QSCALE_));
  }
  f32x4 oA[4] = {{0,0,0,0},{0,0,0,0},{0,0,0,0},{0,0,0,0}};
  f32x4 oB[4] = {{0,0,0,0},{0,0,0,0},{0,0,0,0},{0,0,0,0}};
  float ssA = 0.f, ssB = 0.f;
  const f32x4 accb = {-M0L2_, -M0L2_, -M0L2_, -M0L2_};

  char* kdst = (char*)kk + skey * 144 + kpart * 32;
  char* vdst = (char*)vv + vdb * 144 + kpi * 4;
  const char* kq = (const char*)kk + q * 144 + g * 16;
  const char* vq = (const char*)vv + q * 144 + g * 16;
  char* pw = (char*)pbuf + w * 1280 + q * 80;

  const uint4 z4 = make_uint4(0, 0, 0, 0);
  uint4 kp0, kp1, va, vb_;

#define LLOADK(T) { const int kr = kidx[T]; \
    if (kr >= 0) { const uint4* s = (const uint4*)(Kb + (hN + SINK_ + kr) * 64 + kpart * 16); \
      kp0 = s[0]; kp1 = s[1]; } else { kp0 = z4; kp1 = z4; } }
#define LLOADV(T) { const int r0 = vi0[T], r1 = vi1[T]; \
    va  = (r0 >= 0) ? *(const uint4*)(Vb + (hN + SINK_ + r0) * 64 + vdb) : z4; \
    vb_ = (r1 >= 0) ? *(const uint4*)(Vb + (hN + SINK_ + r1) * 64 + vdb) : z4; }

  LLOADK(0) LLOADV(0)

  for (int t = 0; t < 4; ++t) {
    __syncthreads();
    *(uint4*)kdst = kp0; *(uint4*)(kdst + 16) = kp1;
#define VP(JW, AW, BW) { \
    *(uint*)(vdst + (2*(JW)) * 144) = (AW & 0xffffu) | (BW << 16); \
    *(uint*)(vdst + (2*(JW) + 1) * 144) = (AW >> 16) | (BW & 0xffff0000u); }
    VP(0, va.x, vb_.x) VP(1, va.y, vb_.y) VP(2, va.z, vb_.z) VP(3, va.w, vb_.w)
#undef VP
    if (which == 1 && tid < 64) bias_s[tid] = biasr[t];
    __syncthreads();
    if (t + 1 < 4) { LLOADK(t + 1) LLOADV(t + 1) }

    f32x4 sA[4], sB[4];
    __builtin_amdgcn_s_setprio(1);
#pragma unroll
    for (int st = 0; st < 4; ++st) {
      B8 ka, kb2;
      ka.u  = *(const uint4*)(kq + (st * 16) * 144);
      kb2.u = *(const uint4*)(kq + (st * 16) * 144 + 64);
      f32x4 acc = accb;
      acc = mfma16(ka, qbA0, acc); acc = mfma16(kb2, qbA1, acc);
      sA[st] = acc;
      f32x4 acc2 = accb;
      acc2 = mfma16(ka, qbB0, acc2); acc2 = mfma16(kb2, qbB1, acc2);
      sB[st] = acc2;
    }
    __builtin_amdgcn_s_setprio(0);
    if (which == 1) {
      const f32x4* bp = (const f32x4*)bias_s;
#pragma unroll
      for (int st = 0; st < 4; ++st) {
        sA[st] = sA[st] + bp[st * 4 + g];
        sB[st] = sB[st] + bp[st * 4 + g];
      }
    }

    nomax_sm(sA, ssA);
    pv144(sA, oA, vq, pw, g);
    nomax_sm(sB, ssB);
    pv144(sB, oB, vq, pw, g);
  }
#undef LLOADK
#undef LLOADV

  ssA += __shfl_xor(ssA, 16); ssA += __shfl_xor(ssA, 32);
  ssB += __shfl_xor(ssB, 16); ssB += __shfl_xor(ssB, 32);
  const size_t obase = (size_t)which * 16 * NL_;
#pragma unroll
  for (int fr = 0; fr < 2; ++fr) {
    const int p = fr == 0 ? pA : pB;
    if (p >= NL_) continue;
    const int qi = fr == 0 ? qiA : qiB;
    f32x4* o = fr == 0 ? oA : oB;
    const float ss = fr == 0 ? ssA : ssB;
    const float un = M0_ + __logf(ss);
    const float inv = 1.f / ss;
    store_o_bf16(attn3b + (obase + (size_t)h * NL_ + qi) * 64, o, inv, g);
    if (lane < 16) lse3[obase + h * NL_ + qi] = un;
  }
}

// ---------------- sink prefix (no-max, ILP) + full ordered merge (bf16 partials) ----------------
__global__ __launch_bounds__(256) void kern_final(
    const float* __restrict__ Q, const float* __restrict__ K, const float* __restrict__ V,
    const ushort* __restrict__ tailb, const float* __restrict__ tail_lse,
    const ushort* __restrict__ attn2b, const float* __restrict__ lse2,
    const ushort* __restrict__ attn3b, const float* __restrict__ lse3,
    float* __restrict__ out) {
  const int h = blockIdx.x;
  const int r = blockIdx.y * 256 + (int)threadIdx.x;

  __shared__ float4 kk[SINK_ * 16];
  __shared__ float4 vv[SINK_ * 16];
  for (int u = threadIdx.x; u < SINK_ * 16; u += 256) {
    const int row = u >> 4, d4 = u & 15;
    kk[u] = ((const float4*)(K + ((size_t)h * N_ + row) * 64))[d4];
    vv[u] = ((const float4*)(V + ((size_t)h * N_ + row) * 64))[d4];
  }
  __syncthreads();

  float4 q4[16], acc[16];
  const float4* qp = (const float4*)(Q + ((size_t)h * N_ + r) * 64);
#pragma unroll
  for (int d = 0; d < 16; ++d) { q4[d] = qp[d]; acc[d] = make_float4(0.f, 0.f, 0.f, 0.f); }

  float ssum = 0.f;
  const int nk = min(SINK_, r + 1);
  for (int j = 0; j < nk; ++j) {
    float s = 0.f;
#pragma unroll
    for (int d = 0; d < 16; ++d) {
      float4 x = q4[d], y = kk[j * 16 + d];
      s = fmaf(x.x, y.x, s); s = fmaf(x.y, y.y, s);
      s = fmaf(x.z, y.z, s); s = fmaf(x.w, y.w, s);
    }
    const float wgt = __expf(fmaf(s, SCALE_, -M0_));
    ssum += wgt;
    const float4* v4 = &vv[j * 16];
#pragma unroll
    for (int d = 0; d < 16; ++d) {
      acc[d].x = fmaf(wgt, v4[d].x, acc[d].x);
      acc[d].y = fmaf(wgt, v4[d].y, acc[d].y);
      acc[d].z = fmaf(wgt, v4[d].z, acc[d].z);
      acc[d].w = fmaf(wgt, v4[d].w, acc[d].w);
    }
  }
  const float pl = M0_ + __logf(ssum);
  const float inv = 1.f / ssum;
  float4* op = (float4*)(out + ((size_t)h * N_ + r) * 64);
  if (r < SINK_) {
#pragma unroll
    for (int d = 0; d < 16; ++d)
      op[d] = make_float4(acc[d].x * inv, acc[d].y * inv, acc[d].z * inv, acc[d].w * inv);
    return;
  }

  const int t = r - SINK_;
  float a[64];
  {
    const uint4* tp = (const uint4*)(tailb + ((size_t)h * NT_ + t) * 64);
#pragma unroll
    for (int j = 0; j < 8; ++j) {
      const uint4 u = tp[j];
      a[8*j+0] = bl_(u.x); a[8*j+1] = bh_(u.x);
      a[8*j+2] = bl_(u.y); a[8*j+3] = bh_(u.y);
      a[8*j+4] = bl_(u.z); a[8*j+5] = bh_(u.z);
      a[8*j+6] = bl_(u.w); a[8*j+7] = bh_(u.w);
    }
  }
  float al = tail_lse[h * NT_ + t];

  const int pp = (t >= NL_) ? 1 : 0;
  const int tloc = t - pp * NL_;
  if (tloc >= 1016) {   // P2 merge (split-K halves combined exactly, then into P1)
    const int vh = h * 2 + pp, i = tloc - 1016;
    const float l20 = lse2[vh * 1016 + i];
    const float l21 = lse2[32 * 1016 + vh * 1016 + i];
    const float c12 = 1.f / (1.f + __expf(l21 - l20));
    const float l2 = logaddexpf_(l20, l21);
    const float c = 1.f / (1.f + __expf(l2 - al));
    const uint4* b0 = (const uint4*)(attn2b + ((size_t)(vh * 1016 + i)) * 64);
    const uint4* b1 = (const uint4*)(attn2b + ((size_t)(32 * 1016 + vh * 1016 + i)) * 64);
#pragma unroll
    for (int j = 0; j < 8; ++j) {
      const uint4 u0 = b0[j], u1 = b1[j];
      float x0[8] = {bl_(u0.x), bh_(u0.x), bl_(u0.y), bh_(u0.y), bl_(u0.z), bh_(u0.z), bl_(u0.w), bh_(u0.w)};
      float x1[8] = {bl_(u1.x), bh_(u1.x), bl_(u1.y), bh_(u1.y), bl_(u1.z), bh_(u1.z), bl_(u1.w), bh_(u1.w)};
#pragma unroll
      for (int e = 0; e < 8; ++e) {
        const float bb = c12 * x0[e] + (1.f - c12) * x1[e];
        a[8*j+e] = c * a[8*j+e] + (1.f - c) * bb;
      }
    }
    al = logaddexpf_(al, l2);
  }
  if (t >= NL_) {       // LSH merge: add_self(block, res), then into tail
    const int qi = t - NL_;
    const float l3a = lse3[h * NL_ + qi];
    const float l3b = lse3[16 * NL_ + h * NL_ + qi];
    const float c34 = 1.f / (1.f + __expf(l3b - l3a));
    const float l3 = logaddexpf_(l3a, l3b);
    const float c = 1.f / (1.f + __expf(l3 - al));
    const uint4* b0 = (const uint4*)(attn3b + ((size_t)(h * NL_ + qi)) * 64);
    const uint4* b1 = (const uint4*)(attn3b + ((size_t)(16 * NL_ + h * NL_ + qi)) * 64);
#pragma unroll
    for (int j = 0; j < 8; ++j) {
      const uint4 u0 = b0[j], u1 = b1[j];
      float x0[8] = {bl_(u0.x), bh_(u0.x), bl_(u0.y), bh_(u0.y), bl_(u0.z), bh_(u0.z), bl_(u0.w), bh_(u0.w)};
      float x1[8] = {bl_(u1.x), bh_(u1.x), bl_(u1.y), bh_(u1.y), bl_(u1.z), bh_(u1.z), bl_(u1.w), bh_(u1.w)};
#pragma unroll
      for (int e = 0; e < 8; ++e) {
        const float bb = c34 * x0[e] + (1.f - c34) * x1[e];
        a[8*j+e] = c * a[8*j+e] + (1.f - c) * bb;
      }
    }
    al = logaddexpf_(al, l3);
  }
  const float cc = 1.f / (1.f + __expf(al - pl));
#pragma unroll
  for (int d = 0; d < 16; ++d)
    op[d] = make_float4(cc * acc[d].x * inv + (1.f - cc) * a[4*d+0],
                        cc * acc[d].y * inv + (1.f - cc) * a[4*d+1],
                        cc * acc[d].z * inv + (1.f - cc) * a[4*d+2],
                        cc * acc[d].w * inv + (1.f - cc) * a[4*d+3]);
}

// ---------------- host ----------------
extern "C" void kernel_launch(void* const* d_in, const int* in_sizes, int n_in,
                              void* d_out, int out_size, void* d_ws, size_t ws_size,
                              hipStream_t stream) {
  (void)in_sizes; (void)n_in; (void)out_size; (void)ws_size;
  const float* Q = (const float*)d_in[0];
  const float* K = (const float*)d_in[1];
  const float* V = (const float*)d_in[2];
  const float* proj = (const float*)d_in[3];
  float* out = (float*)d_out;

  char* w = (char*)d_ws;
  auto carve = [&](size_t bytes) { char* p = w; w += (bytes + 255) & ~(size_t)255; return p; };
  ushort* tailb  = (ushort*)carve((size_t)H_ * NT_ * 64 * sizeof(ushort));
  float* tail_lse = (float*)carve((size_t)H_ * NT_ * sizeof(float));
  ushort* attn2b = (ushort*)carve((size_t)2 * 32 * 1016 * 64 * sizeof(ushort));
  float* lse2    = (float*)carve((size_t)2 * 32 * 1016 * sizeof(float));
  ushort* attn3b = (ushort*)carve((size_t)2 * H_ * NL_ * 64 * sizeof(ushort));
  float* lse3    = (float*)carve((size_t)2 * H_ * NL_ * sizeof(float));
  ushort* Kb     = (ushort*)carve((size_t)H_ * N_ * 64 * sizeof(ushort));
  ushort* Vb     = (ushort*)carve((size_t)H_ * N_ * 64 * sizeof(ushort));
  ushort* Vt     = (ushort*)carve((size_t)H_ * N_ * 64 * sizeof(ushort) + 4096);
  int* hq        = (int*)carve((size_t)H_ * NL_ * sizeof(int));
  int* hk        = (int*)carve((size_t)H_ * NL_ * sizeof(int));
  int* q_sort    = (int*)carve((size_t)H_ * NL_ * sizeof(int));
  int* k_sort    = (int*)carve((size_t)H_ * NL_ * sizeof(int));
  int* samp_pos  = (int*)carve((size_t)H_ * SAMP_ * sizeof(int));
  int* samp_orig = (int*)carve((size_t)H_ * SAMP_ * sizeof(int));

  kern_packhash<<<dim3(3328), 256, 0, stream>>>(K, V, Q, proj, Kb, Vb, Vt, hq, hk);
  kern_sortsamp<<<dim3(H_, 2), 256, 0, stream>>>(hq, hk, q_sort, k_sort, samp_pos, samp_orig);
  kern_attn_mfma<<<dim3(1024), 256, 0, stream>>>(Q, Kb, Vt, tailb, tail_lse, attn2b, lse2);
  kern_lsh_mfma<<<dim3(512), 256, 0, stream>>>(Q, Kb, Vb, q_sort, k_sort, samp_pos, samp_orig,
                                               attn3b, lse3);
  kern_final<<<dim3(H_, 16), 256, 0, stream>>>(Q, K, V, tailb, tail_lse,
                                               attn2b, lse2, attn3b, lse3, out);
}

// Round 14
// 127.842 us; speedup vs baseline: 1.0800x; 1.0043x over previous
//
#include <hip/hip_runtime.h>
#include <hip/hip_bf16.h>
#include <math.h>
#include <stdint.h>

#define H_ 16
#define N_ 4096
#define NT_ 4064        // tail length
#define NL_ 2032        // LSH segment length
#define SINK_ 32
#define SAMP_ 256
#define SCALE_ 0.125f
#define QSCALE_ 0.18033688f    // 0.125 * log2(e)
#define M0L2_ 11.5415606f      // 8 * log2(e)
#define M0_ 8.0f
#define NEGBIG_ -3.0e38f
#define LOGOFF_L2_ 2.9886841f  // log2(2032/256)

typedef unsigned int uint;
typedef unsigned short ushort;
typedef short bf16x8 __attribute__((ext_vector_type(8)));
typedef float f32x4 __attribute__((ext_vector_type(4)));

union B8 { uint4 u; bf16x8 b; };

__device__ __forceinline__ f32x4 mfma16(const B8& a, const B8& b, f32x4 c) {
  return __builtin_amdgcn_mfma_f32_16x16x32_bf16(a.b, b.b, c, 0, 0, 0);
}

__device__ __forceinline__ uint bfpack(float a, float b) {
  uint ua = __float_as_uint(a), ub = __float_as_uint(b);
  ua += 0x7fffu + ((ua >> 16) & 1u);
  ub += 0x7fffu + ((ub >> 16) & 1u);
  return (ua >> 16) | (ub & 0xffff0000u);
}

__device__ __forceinline__ uint cvtpk(float a, float b) {
  union { __hip_bfloat162 h; uint u; } r;
  r.h.x = __float2bfloat16(a);
  r.h.y = __float2bfloat16(b);
  return r.u;
}

__device__ __forceinline__ float bl_(uint u) { return __uint_as_float(u << 16); }
__device__ __forceinline__ float bh_(uint u) { return __uint_as_float(u & 0xffff0000u); }

__device__ __forceinline__ float logaddexpf_(float a, float b) {
  float mx = fmaxf(a, b);
  return mx + __logf(__expf(a - mx) + __expf(b - mx));
}

__device__ __forceinline__ uint32_t rotl32_(uint32_t v, uint32_t d) {
  return (v << d) | (v >> (32u - d));
}

// JAX threefry2x32 (20 rounds)
__device__ inline void tf2x32(uint32_t k0, uint32_t k1, uint32_t& x0, uint32_t& x1) {
  uint32_t ks2 = k0 ^ k1 ^ 0x1BD11BDAu;
  x0 += k0; x1 += k1;
#define TFR(r) { x0 += x1; x1 = rotl32_(x1, r); x1 ^= x0; }
  TFR(13u) TFR(15u) TFR(26u) TFR(6u)
  x0 += k1;  x1 += ks2 + 1u;
  TFR(17u) TFR(29u) TFR(16u) TFR(24u)
  x0 += ks2; x1 += k0 + 2u;
  TFR(13u) TFR(15u) TFR(26u) TFR(6u)
  x0 += k0;  x1 += k1 + 3u;
  TFR(17u) TFR(29u) TFR(16u) TFR(24u)
  x0 += k1;  x1 += ks2 + 4u;
  TFR(13u) TFR(15u) TFR(26u) TFR(6u)
  x0 += ks2; x1 += k0 + 5u;
#undef TFR
}

// ---------------- fixed-offset softmax ----------------
__device__ __forceinline__ void nomax_sm(f32x4 s[4], float& ssum) {
#pragma unroll
  for (int st = 0; st < 4; ++st)
#pragma unroll
    for (int r = 0; r < 4; ++r) {
      s[st][r] = __builtin_exp2f(s[st][r]);
      ssum += s[st][r];
    }
}

// pbuf XOR-swizzled write/read (R4-proven): per-wave 1024B region, per-q 64B row
#define PB_WRITE(SS, HK2) { \
  const f32x4 pa_ = SS[2*(HK2)], pc_ = SS[2*(HK2)+1]; \
  *(uint2*)(pw + ((((g >> 1)    ) ^ (q & 3)) * 16) + (g & 1) * 8) = \
      make_uint2(cvtpk(pa_[0], pa_[1]), cvtpk(pa_[2], pa_[3])); \
  *(uint2*)(pw + (((2 + (g >> 1)) ^ (q & 3)) * 16) + (g & 1) * 8) = \
      make_uint2(cvtpk(pc_[0], pc_[1]), cvtpk(pc_[2], pc_[3])); }
#define PB_READ(PF) { (PF).u = *(const uint4*)(pw + ((g ^ (q & 3)) * 16)); }

// bf16 epilogue store
__device__ __forceinline__ void store_o_bf16(ushort* tp, const f32x4 o[4], float inv, int g) {
#pragma unroll
  for (int d = 0; d < 4; ++d) {
    const f32x4 r = o[d] * inv;
    *(uint2*)(tp + d * 16 + 4 * g) = make_uint2(cvtpk(r[0], r[1]), cvtpk(r[2], r[3]));
  }
}

// =========================================================================
// pack: blocks 0..2047 K bf16 linear; 2048..3071 V transpose; 3072..3327 hash.
// =========================================================================
__global__ __launch_bounds__(256) void kern_packhash(
    const float* __restrict__ K, const float* __restrict__ V, const float* __restrict__ Q,
    const float* __restrict__ proj,
    ushort* __restrict__ Kb, ushort* __restrict__ Vb, ushort* __restrict__ Vt,
    int* __restrict__ hq, int* __restrict__ hk) {
  const int bb = blockIdx.x;
  const int tid = threadIdx.x;
  if (bb < 2048) {               // ---- K linear pack ----
    const size_t idx = (size_t)bb * 256 + tid;
    const float4* s = (const float4*)(K + idx * 8);
    float4 f0 = s[0], f1 = s[1];
    uint4 p = make_uint4(bfpack(f0.x, f0.y), bfpack(f0.z, f0.w),
                         bfpack(f1.x, f1.y), bfpack(f1.z, f1.w));
    *(uint4*)(Kb + idx * 8) = p;
    return;
  }
  if (bb < 3072) {               // ---- V transpose + row pack ----
    __shared__ ushort tr[64 * 72];
    const int u = bb - 2048;
    const int h = u >> 6, nt = u & 63;
    const int n0 = nt * 64;
    const size_t hN = (size_t)h * N_;
    const int nloc = tid >> 2, dpart = (tid & 3) * 16;
    const float4* src = (const float4*)(V + (hN + n0 + nloc) * 64 + dpart);
    float4 f0 = src[0], f1 = src[1], f2 = src[2], f3 = src[3];
    uint p0 = bfpack(f0.x, f0.y), p1 = bfpack(f0.z, f0.w);
    uint p2 = bfpack(f1.x, f1.y), p3 = bfpack(f1.z, f1.w);
    uint p4 = bfpack(f2.x, f2.y), p5 = bfpack(f2.z, f2.w);
    uint p6 = bfpack(f3.x, f3.y), p7 = bfpack(f3.z, f3.w);
    ushort* vbdst = Vb + (hN + n0 + nloc) * 64 + dpart;
    ((uint4*)vbdst)[0] = make_uint4(p0, p1, p2, p3);
    ((uint4*)vbdst)[1] = make_uint4(p4, p5, p6, p7);
    uint pv[8] = {p0, p1, p2, p3, p4, p5, p6, p7};
#pragma unroll
    for (int j = 0; j < 8; ++j) {
      tr[(dpart + 2 * j    ) * 72 + nloc] = (ushort)(pv[j] & 0xffffu);
      tr[(dpart + 2 * j + 1) * 72 + nloc] = (ushort)(pv[j] >> 16);
    }
    __syncthreads();
    const int d = tid >> 2, np = (tid & 3) * 16;
    const uint4* tp = (const uint4*)(tr + d * 72 + np);
    uint4 t0 = tp[0], t1 = tp[1];
    ushort* dst = Vt + ((size_t)(h * 64 + d)) * 4096 + n0 + np;
    ((uint4*)dst)[0] = t0;
    ((uint4*)dst)[1] = t1;
    return;
  }
  // ---- hash ----
  __shared__ float pr[448];
  const int u = bb - 3072;
  const int h = u & 15, tile = (u >> 4) & 7, which = u >> 7;
  for (int t = tid; t < 448; t += 256) pr[t] = proj[t];
  __syncthreads();
  const int i = tile * 256 + tid;
  if (i >= NL_) return;
  const int orig = (which == 0) ? (SINK_ + NL_ + i) : (SINK_ + i);
  const float4* x = (const float4*)((which == 0 ? Q : K) + ((size_t)h * N_ + orig) * 64);
  float xr[64];
#pragma unroll
  for (int d = 0; d < 16; ++d) {
    float4 g = x[d];
    xr[4*d+0] = g.x; xr[4*d+1] = g.y; xr[4*d+2] = g.z; xr[4*d+3] = g.w;
  }
  int bin = 0;
#pragma unroll
  for (int r = 0; r < 7; ++r) {
    float acc = 0.f;
#pragma unroll
    for (int d = 0; d < 64; ++d) acc = fmaf(xr[d], pr[d * 7 + r], acc);
    if (acc > 0.f) bin |= (1 << r);
  }
  const int g = bin ^ (bin >> 1);
  (which == 0 ? hq : hk)[h * NL_ + i] = g;
}

// ---------------- chunked stable counting sort + threefry sample ----------------
__global__ __launch_bounds__(256) void kern_sortsamp(
    const int* __restrict__ hq, const int* __restrict__ hk,
    int* __restrict__ q_sort, int* __restrict__ k_sort,
    int* __restrict__ samp_pos, int* __restrict__ samp_orig) {
  const int h = blockIdx.x, which = blockIdx.y;
  const int tid = threadIdx.x;

  __shared__ unsigned char keys8[NL_];
  __shared__ ushort M[64 * 130];
  __shared__ int btot[128];
  __shared__ int bscan[128];
  __shared__ ushort srt[NL_];

  const int* src = (which == 0 ? hq : hk) + h * NL_;
  for (int u = tid; u < 64 * 130 / 2; u += 256) ((uint*)M)[u] = 0u;
  for (int u = tid; u < NL_; u += 256) keys8[u] = (unsigned char)src[u];
  __syncthreads();

  if (tid < 64) {
    const int c = tid;
#pragma unroll 4
    for (int j = 0; j < 32; ++j) {
      const int u = c * 32 + j;
      if (u < NL_) ++M[c * 130 + keys8[u]];
    }
  }
  __syncthreads();

  if (tid < 128) {
    const int b = tid;
    int run = 0;
    for (int c = 0; c < 64; ++c) {
      const int v = M[c * 130 + b];
      M[c * 130 + b] = (ushort)run;
      run += v;
    }
    btot[b] = run;
    bscan[b] = run;
  }
  __syncthreads();

  for (int ofs = 1; ofs < 128; ofs <<= 1) {
    int v = 0;
    if (tid < 128 && tid >= ofs) v = bscan[tid - ofs];
    __syncthreads();
    if (tid < 128) bscan[tid] += v;
    __syncthreads();
  }

  int* dst = (which == 0 ? q_sort : k_sort) + h * NL_;
  if (tid < 64) {
    const int c = tid;
    for (int j = 0; j < 32; ++j) {
      const int u = c * 32 + j;
      if (u < NL_) {
        const int k = keys8[u];
        const int pos = (bscan[k] - btot[k]) + M[c * 130 + k];
        M[c * 130 + k] += 1;
        dst[pos] = u;
        srt[pos] = (ushort)u;
      }
    }
  }
  __syncthreads();

  if (which == 1) {
    const int s = tid;
    uint32_t a0 = 0u, a1 = 0u; tf2x32(0u, 1234u, a0, a1);
    uint32_t b0 = 0u, b1 = 0u; tf2x32(a0, a1, b0, b1);
    uint32_t c0 = 0u, c1 = 1u; tf2x32(a0, a1, c0, c1);
    const uint32_t j = (uint32_t)(h * SAMP_ + s);
    uint32_t h0 = 0u, h1 = j; tf2x32(b0, b1, h0, h1);
    uint32_t l0 = 0u, l1 = j; tf2x32(c0, c1, l0, l1);
    const uint32_t Hb = h0 ^ h1, Lb = l0 ^ l1;
    const uint32_t off = ((Hb % 2032u) * 16u + (Lb % 2032u)) % 2032u;
    samp_pos[h * SAMP_ + s] = (int)off;
    samp_orig[h * SAMP_ + s] = (int)srt[off];
  }
}

// =========================================================================
// MFMA flash attention (R11/R13 structure). Grid 1024.
// LDS: kk 18432 + vv 17408 + pbuf 4096 = 39936 B (margin under 160KB/4).
// PV fused across both q-frags: each vf LDS read feeds oA and oB.
// =========================================================================
__global__ __launch_bounds__(256) void kern_attn_mfma(
    const float* __restrict__ Q, const ushort* __restrict__ Kb, const ushort* __restrict__ Vt,
    ushort* __restrict__ tailb, float* __restrict__ tail_lse,
    ushort* __restrict__ attn2b, float* __restrict__ lse2) {
  __shared__ uint kk[4608];    // 18432 B
  __shared__ uint vv[4352];    // 17408 B
  __shared__ uint pbuf[1024];  // 4096 B

  const int b = blockIdx.x;
  const int tid = threadIdx.x;
  const int lane = tid & 63, w = tid >> 6;
  const int g = lane >> 4, q = lane & 15;
  const uint4 z4 = make_uint4(0, 0, 0, 0);
  const f32x4 accb = {-M0L2_, -M0L2_, -M0L2_, -M0L2_};

  int h, q0, qbase, kbase, ntiles, klen, p2slot = 0, chunkc = 0;
  bool causal;
  if (b < 512) {                       // P1: LPT descending qt
    const int u = b; const int vh = u & 63;
    const int qt = 7 - (u >> 6);
    h = vh >> 2; chunkc = vh & 3;
    q0 = qt * 128;
    qbase = SINK_ + chunkc * 1016;
    kbase = qbase;
    ntiles = qt + 1; causal = true; klen = 1016;
  } else {                             // P2 split-K halves
    const int u = b - 512; const int vh = u & 31; const int qt = (u >> 5) & 7;
    const int hf = u >> 8;
    h = vh >> 1; const int pp = vh & 1;
    q0 = qt * 128;
    qbase = SINK_ + pp * 2032 + 1016;
    kbase = SINK_ + pp * 2032 + hf * 512;
    ntiles = 4; causal = false; klen = hf ? 504 : 512;
    p2slot = hf * 32 * 1016 + vh * 1016;
  }
  const size_t hN = (size_t)h * N_;
  const int qrowA = q0 + w * 16 + q;
  const int qrowB = qrowA + 64;
  const int qcA = min(qrowA, 1015), qcB = min(qrowB, 1015);
  const int qwA_lo = q0 + w * 16, qwmaxA = qwA_lo + 15;
  const int qwB_lo = qwA_lo + 64;

  B8 qbA0, qbA1, qbB0, qbB1;
  {
    const float4* qp = (const float4*)(Q + (hN + qbase + qcA) * 64);
    float4 a = qp[2*g], c = qp[2*g+1], d = qp[8+2*g], e = qp[8+2*g+1];
    qbA0.u = make_uint4(bfpack(a.x*QSCALE_, a.y*QSCALE_), bfpack(a.z*QSCALE_, a.w*QSCALE_),
                        bfpack(c.x*QSCALE_, c.y*QSCALE_), bfpack(c.z*QSCALE_, c.w*QSCALE_));
    qbA1.u = make_uint4(bfpack(d.x*QSCALE_, d.y*QSCALE_), bfpack(d.z*QSCALE_, d.w*QSCALE_),
                        bfpack(e.x*QSCALE_, e.y*QSCALE_), bfpack(e.z*QSCALE_, e.w*QSCALE_));
    const float4* qp2 = (const float4*)(Q + (hN + qbase + qcB) * 64);
    a = qp2[2*g]; c = qp2[2*g+1]; d = qp2[8+2*g]; e = qp2[8+2*g+1];
    qbB0.u = make_uint4(bfpack(a.x*QSCALE_, a.y*QSCALE_), bfpack(a.z*QSCALE_, a.w*QSCALE_),
                        bfpack(c.x*QSCALE_, c.y*QSCALE_), bfpack(c.z*QSCALE_, c.w*QSCALE_));
    qbB1.u = make_uint4(bfpack(d.x*QSCALE_, d.y*QSCALE_), bfpack(d.z*QSCALE_, d.w*QSCALE_),
                        bfpack(e.x*QSCALE_, e.y*QSCALE_), bfpack(e.z*QSCALE_, e.w*QSCALE_));
  }
  f32x4 oA[4] = {{0,0,0,0},{0,0,0,0},{0,0,0,0},{0,0,0,0}};
  f32x4 oB[4] = {{0,0,0,0},{0,0,0,0},{0,0,0,0},{0,0,0,0}};
  float ssA = 0.f, ssB = 0.f;

  const int krow_l = tid >> 1, kpart = tid & 1;
  const int vrow = tid >> 2, vc32 = tid & 3;
  char* kdst = (char*)kk + krow_l * 144 + kpart * 64;
  char* vdst = (char*)vv + vrow * 272 + vc32 * 64;
  const char* kq = (const char*)kk + q * 144 + g * 16;
  const char* vq = (const char*)vv + q * 272 + g * 16;
  char* pw = (char*)pbuf + w * 1024 + q * 64;
  const size_t vtbase = ((size_t)(h * 64 + vrow)) * 4096 + kbase + vc32 * 32;

  uint4 kp0, kp1, kp2, kp3, va, va2, vb_, vb2;

#define LOADK(T) { const int kr = (T) * 128 + krow_l; \
    if (kr < klen) { const uint4* s = (const uint4*)(Kb + (hN + kbase + kr) * 64 + kpart * 32); \
      kp0 = s[0]; kp1 = s[1]; kp2 = s[2]; kp3 = s[3]; } \
    else { kp0 = z4; kp1 = z4; kp2 = z4; kp3 = z4; } }
#define LOADV(T) { const uint4* sv = (const uint4*)(Vt + vtbase + (size_t)(T) * 128); \
    va = sv[0]; va2 = sv[1]; vb_ = sv[2]; vb2 = sv[3]; }

  LOADK(0) LOADV(0)

  for (int t = 0; t < ntiles; ++t) {
    const int kt = t * 128;
    __syncthreads();
    *(uint4*)kdst = kp0; *(uint4*)(kdst + 16) = kp1;
    *(uint4*)(kdst + 32) = kp2; *(uint4*)(kdst + 48) = kp3;
    *(uint4*)vdst = va; *(uint4*)(vdst + 16) = va2;
    *(uint4*)(vdst + 32) = vb_; *(uint4*)(vdst + 48) = vb2;
    __syncthreads();
    if (t + 1 < ntiles) { LOADK(t + 1) LOADV(t + 1) }

#pragma unroll
    for (int u2 = 0; u2 < 2; ++u2) {
      const int hb = kt + u2 * 64;
      const bool dA = !(causal && hb > qwmaxA);
      f32x4 sA[4], sB[4];
      __builtin_amdgcn_s_setprio(1);
#pragma unroll
      for (int st = 0; st < 4; ++st) {
        B8 ka, kb2;
        ka.u  = *(const uint4*)(kq + (u2 * 64 + st * 16) * 144);
        kb2.u = *(const uint4*)(kq + (u2 * 64 + st * 16) * 144 + 64);
        if (dA) {
          f32x4 acc = accb;
          acc = mfma16(ka, qbA0, acc); acc = mfma16(kb2, qbA1, acc);
          sA[st] = acc;
        }
        f32x4 acc2 = accb;
        acc2 = mfma16(ka, qbB0, acc2); acc2 = mfma16(kb2, qbB1, acc2);
        sB[st] = acc2;
      }
      __builtin_amdgcn_s_setprio(0);

      if (causal) {
        const int kb0 = hb + 4 * g;
        if (dA && hb + 63 > qwA_lo) {
#pragma unroll
          for (int st = 0; st < 4; ++st)
#pragma unroll
            for (int r = 0; r < 4; ++r)
              if (kb0 + st * 16 + r > qrowA) sA[st][r] = NEGBIG_;
        }
        if (hb + 63 > qwB_lo) {
#pragma unroll
          for (int st = 0; st < 4; ++st)
#pragma unroll
            for (int r = 0; r < 4; ++r)
              if (kb0 + st * 16 + r > qrowB) sB[st][r] = NEGBIG_;
        }
      } else if (hb + 63 >= klen) {
        const int kb0 = hb + 4 * g;
#pragma unroll
        for (int st = 0; st < 4; ++st)
#pragma unroll
          for (int r = 0; r < 4; ++r)
            if (kb0 + st * 16 + r >= klen) { sA[st][r] = NEGBIG_; sB[st][r] = NEGBIG_; }
      }

      if (dA) {
        nomax_sm(sA, ssA);
        nomax_sm(sB, ssB);
        // fused PV: each vf read feeds both frags
        __builtin_amdgcn_s_setprio(1);
#pragma unroll
        for (int hk2 = 0; hk2 < 2; ++hk2) {
          B8 pfA, pfB, vf;
          PB_WRITE(sA, hk2) PB_READ(pfA)
          PB_WRITE(sB, hk2) PB_READ(pfB)
          const int vo = u2 * 128 + hk2 * 64;
          vf.u = *(const uint4*)(vq + 0 * 4352 + vo);
          oA[0] = mfma16(vf, pfA, oA[0]); oB[0] = mfma16(vf, pfB, oB[0]);
          vf.u = *(const uint4*)(vq + 1 * 4352 + vo);
          oA[1] = mfma16(vf, pfA, oA[1]); oB[1] = mfma16(vf, pfB, oB[1]);
          vf.u = *(const uint4*)(vq + 2 * 4352 + vo);
          oA[2] = mfma16(vf, pfA, oA[2]); oB[2] = mfma16(vf, pfB, oB[2]);
          vf.u = *(const uint4*)(vq + 3 * 4352 + vo);
          oA[3] = mfma16(vf, pfA, oA[3]); oB[3] = mfma16(vf, pfB, oB[3]);
        }
        __builtin_amdgcn_s_setprio(0);
      } else {
        nomax_sm(sB, ssB);
        __builtin_amdgcn_s_setprio(1);
#pragma unroll
        for (int hk2 = 0; hk2 < 2; ++hk2) {
          B8 pfB, vf;
          PB_WRITE(sB, hk2) PB_READ(pfB)
          const int vo = u2 * 128 + hk2 * 64;
          vf.u = *(const uint4*)(vq + 0 * 4352 + vo); oB[0] = mfma16(vf, pfB, oB[0]);
          vf.u = *(const uint4*)(vq + 1 * 4352 + vo); oB[1] = mfma16(vf, pfB, oB[1]);
          vf.u = *(const uint4*)(vq + 2 * 4352 + vo); oB[2] = mfma16(vf, pfB, oB[2]);
          vf.u = *(const uint4*)(vq + 3 * 4352 + vo); oB[3] = mfma16(vf, pfB, oB[3]);
        }
        __builtin_amdgcn_s_setprio(0);
      }
    }
  }
#undef LOADK
#undef LOADV

  ssA += __shfl_xor(ssA, 16); ssA += __shfl_xor(ssA, 32);
  ssB += __shfl_xor(ssB, 16); ssB += __shfl_xor(ssB, 32);
#pragma unroll
  for (int fr = 0; fr < 2; ++fr) {
    const int qrow = fr == 0 ? qrowA : qrowB;
    if (qrow >= 1016) continue;
    f32x4* o = fr == 0 ? oA : oB;
    const float ss = fr == 0 ? ssA : ssB;
    const float lse = M0_ + __logf(ss);
    const float inv = 1.f / ss;
    if (causal) {
      const int trow = chunkc * 1016 + qrow;
      store_o_bf16(tailb + ((size_t)h * NT_ + trow) * 64, o, inv, g);
      if (lane < 16) tail_lse[h * NT_ + trow] = lse;
    } else {
      store_o_bf16(attn2b + ((size_t)(p2slot + qrow)) * 64, o, inv, g);
      if (lane < 16) lse2[p2slot + qrow] = lse;
    }
  }
}

// =========================================================================
// MFMA LSH attention, split per reference: grid 512 -> attn3b (bf16).
// PV fused across both q-frags.
// =========================================================================
__global__ __launch_bounds__(256) void kern_lsh_mfma(
    const float* __restrict__ Q, const ushort* __restrict__ Kb, const ushort* __restrict__ Vb,
    const int* __restrict__ q_sort, const int* __restrict__ k_sort,
    const int* __restrict__ samp_pos, const int* __restrict__ samp_orig,
    ushort* __restrict__ attn3b, float* __restrict__ lse3) {
  __shared__ uint kk[2304];
  __shared__ uint vv[2304];
  __shared__ uint pbuf[1024];
  __shared__ float bias_s[64];

  const int b = blockIdx.x;
  const int which = b >> 8;
  const int bq = b & 255;
  const int h = bq >> 4, pt = bq & 15;
  const int tid = threadIdx.x;
  const int lane = tid & 63, w = tid >> 6;
  const int g = lane >> 4, q = lane & 15;
  const int blkq = pt >> 1;
  const size_t hN = (size_t)h * N_;

  const int pA = pt * 128 + w * 16 + q;
  const int pB = pA + 64;
  const int qiA = q_sort[h * NL_ + min(pA, NL_ - 1)];
  const int qiB = q_sort[h * NL_ + min(pB, NL_ - 1)];

  const int skey = tid >> 2, kpart = tid & 3;
  const int kpi = tid & 31, vdb = (tid >> 5) * 8;
  int kidx[4], vi0[4], vi1[4];
  float biasr[4];
#pragma unroll
  for (int t = 0; t < 4; ++t) {
    if (which == 0) {
      const int slot = blkq * 256 + t * 64 + skey;
      kidx[t] = (slot < NL_) ? k_sort[h * NL_ + slot] : -1;
      const int s0 = blkq * 256 + t * 64 + 2 * kpi;
      vi0[t] = (s0 < NL_) ? k_sort[h * NL_ + s0] : -1;
      vi1[t] = (s0 + 1 < NL_) ? k_sort[h * NL_ + s0 + 1] : -1;
    } else {
      kidx[t] = samp_orig[h * SAMP_ + t * 64 + skey];
      const int si = t * 64 + 2 * kpi;
      vi0[t] = samp_orig[h * SAMP_ + si];
      vi1[t] = samp_orig[h * SAMP_ + si + 1];
    }
  }
  if (which == 1 && tid < 64) {
#pragma unroll
    for (int j = 0; j < 4; ++j)
      biasr[j] = ((samp_pos[h * SAMP_ + j * 64 + tid] >> 8) == blkq) ? NEGBIG_ : LOGOFF_L2_;
  }

  B8 qbA0, qbA1, qbB0, qbB1;
  {
    const float4* qp = (const float4*)(Q + (hN + SINK_ + NL_ + qiA) * 64);
    float4 a = qp[2*g], c = qp[2*g+1], d = qp[8+2*g], e = qp[8+2*g+1];
    qbA0.u = make_uint4(bfpack(a.x*QSCALE_, a.y*QSCALE_), bfpack(a.z*QSCALE_, a.w*QSCALE_),
                        bfpack(c.x*QSCALE_, c.y*QSCALE_), bfpack(c.z*QSCALE_, c.w*QSCALE_));
    qbA1.u = make_uint4(bfpack(d.x*QSCALE_, d.y*QSCALE_), bfpack(d.z*QSCALE_, d.w*QSCALE_),
                        bfpack(e.x*QSCALE_, e.y*QSCALE_), bfpack(e.z*QSCALE_, e.w*QSCALE_));
    const float4* qp2 = (const float4*)(Q + (hN + SINK_ + NL_ + qiB) * 64);
    a = qp2[2*g]; c = qp2[2*g+1]; d = qp2[8+2*g]; e = qp2[8+2*g+1];
    qbB0.u = make_uint4(bfpack(a.x*QSCALE_, a.y*QSCALE_), bfpack(a.z*QSCALE_, a.w*QSCALE_),
                        bfpack(c.x*QSCALE_, c.y*QSCALE_), bfpack(c.z*QSCALE_, c.w*QSCALE_));
    qbB1.u = make_uint4(bfpack(d.x*QSCALE_, d.y*QSCALE_), bfpack(d.z*QSCALE_, d.w*QSCALE_),
                        bfpack(e.x*QSCALE_, e.y*QSCALE_), bfpack(e.z*QSCALE_, e.w*QSCALE_));
  }
  f32x4 oA[4] = {{0,0,0,0},{0,0,0,0},{0,0,0,0},{0,0,0,0}};
  f32x4 oB[4] = {{0,0,0,0},{0,0,0,0},{0,0,0,0},{0,0,0,0}};
  float ssA = 0.f, ssB = 0.f;
  const f32x4 accb = {-M0L2_, -M0L2_, -M0L2_, -M0L2_};

  char* kdst = (char*)kk + skey * 144 + kpart * 32;
  char* vdst = (char*)vv + vdb * 144 + kpi * 4;
  const char* kq = (const char*)kk + q * 144 + g * 16;
  const char* vq = (const char*)vv + q * 144 + g * 16;
  char* pw = (char*)pbuf + w * 1024 + q * 64;

  const uint4 z4 = make_uint4(0, 0, 0, 0);
  uint4 kp0, kp1, va, vb_;

#define LLOADK(T) { const int kr = kidx[T]; \
    if (kr >= 0) { const uint4* s = (const uint4*)(Kb + (hN + SINK_ + kr) * 64 + kpart * 16); \
      kp0 = s[0]; kp1 = s[1]; } else { kp0 = z4; kp1 = z4; } }
#define LLOADV(T) { const int r0 = vi0[T], r1 = vi1[T]; \
    va  = (r0 >= 0) ? *(const uint4*)(Vb + (hN + SINK_ + r0) * 64 + vdb) : z4; \
    vb_ = (r1 >= 0) ? *(const uint4*)(Vb + (hN + SINK_ + r1) * 64 + vdb) : z4; }

  LLOADK(0) LLOADV(0)

  for (int t = 0; t < 4; ++t) {
    __syncthreads();
    *(uint4*)kdst = kp0; *(uint4*)(kdst + 16) = kp1;
#define VP(JW, AW, BW) { \
    *(uint*)(vdst + (2*(JW)) * 144) = (AW & 0xffffu) | (BW << 16); \
    *(uint*)(vdst + (2*(JW) + 1) * 144) = (AW >> 16) | (BW & 0xffff0000u); }
    VP(0, va.x, vb_.x) VP(1, va.y, vb_.y) VP(2, va.z, vb_.z) VP(3, va.w, vb_.w)
#undef VP
    if (which == 1 && tid < 64) bias_s[tid] = biasr[t];
    __syncthreads();
    if (t + 1 < 4) { LLOADK(t + 1) LLOADV(t + 1) }

    f32x4 sA[4], sB[4];
    __builtin_amdgcn_s_setprio(1);
#pragma unroll
    for (int st = 0; st < 4; ++st) {
      B8 ka, kb2;
      ka.u  = *(const uint4*)(kq + (st * 16) * 144);
      kb2.u = *(const uint4*)(kq + (st * 16) * 144 + 64);
      f32x4 acc = accb;
      acc = mfma16(ka, qbA0, acc); acc = mfma16(kb2, qbA1, acc);
      sA[st] = acc;
      f32x4 acc2 = accb;
      acc2 = mfma16(ka, qbB0, acc2); acc2 = mfma16(kb2, qbB1, acc2);
      sB[st] = acc2;
    }
    __builtin_amdgcn_s_setprio(0);
    if (which == 1) {
      const f32x4* bp = (const f32x4*)bias_s;
#pragma unroll
      for (int st = 0; st < 4; ++st) {
        sA[st] = sA[st] + bp[st * 4 + g];
        sB[st] = sB[st] + bp[st * 4 + g];
      }
    }

    nomax_sm(sA, ssA);
    nomax_sm(sB, ssB);
    __builtin_amdgcn_s_setprio(1);
#pragma unroll
    for (int hk2 = 0; hk2 < 2; ++hk2) {
      B8 pfA, pfB, vf;
      PB_WRITE(sA, hk2) PB_READ(pfA)
      PB_WRITE(sB, hk2) PB_READ(pfB)
      const int vo = hk2 * 64;
      vf.u = *(const uint4*)(vq + 0 * 2304 + vo);
      oA[0] = mfma16(vf, pfA, oA[0]); oB[0] = mfma16(vf, pfB, oB[0]);
      vf.u = *(const uint4*)(vq + 1 * 2304 + vo);
      oA[1] = mfma16(vf, pfA, oA[1]); oB[1] = mfma16(vf, pfB, oB[1]);
      vf.u = *(const uint4*)(vq + 2 * 2304 + vo);
      oA[2] = mfma16(vf, pfA, oA[2]); oB[2] = mfma16(vf, pfB, oB[2]);
      vf.u = *(const uint4*)(vq + 3 * 2304 + vo);
      oA[3] = mfma16(vf, pfA, oA[3]); oB[3] = mfma16(vf, pfB, oB[3]);
    }
    __builtin_amdgcn_s_setprio(0);
  }
#undef LLOADK
#undef LLOADV

  ssA += __shfl_xor(ssA, 16); ssA += __shfl_xor(ssA, 32);
  ssB += __shfl_xor(ssB, 16); ssB += __shfl_xor(ssB, 32);
  const size_t obase = (size_t)which * 16 * NL_;
#pragma unroll
  for (int fr = 0; fr < 2; ++fr) {
    const int p = fr == 0 ? pA : pB;
    if (p >= NL_) continue;
    const int qi = fr == 0 ? qiA : qiB;
    f32x4* o = fr == 0 ? oA : oB;
    const float ss = fr == 0 ? ssA : ssB;
    const float un = M0_ + __logf(ss);
    const float inv = 1.f / ss;
    store_o_bf16(attn3b + (obase + (size_t)h * NL_ + qi) * 64, o, inv, g);
    if (lane < 16) lse3[obase + h * NL_ + qi] = un;
  }
}

// ---------------- sink prefix (no-max, ILP) + full ordered merge (bf16 partials) ----------------
__global__ __launch_bounds__(256) void kern_final(
    const float* __restrict__ Q, const float* __restrict__ K, const float* __restrict__ V,
    const ushort* __restrict__ tailb, const float* __restrict__ tail_lse,
    const ushort* __restrict__ attn2b, const float* __restrict__ lse2,
    const ushort* __restrict__ attn3b, const float* __restrict__ lse3,
    float* __restrict__ out) {
  const int h = blockIdx.x;
  const int r = blockIdx.y * 256 + (int)threadIdx.x;

  __shared__ float4 kk[SINK_ * 16];
  __shared__ float4 vv[SINK_ * 16];
  for (int u = threadIdx.x; u < SINK_ * 16; u += 256) {
    const int row = u >> 4, d4 = u & 15;
    kk[u] = ((const float4*)(K + ((size_t)h * N_ + row) * 64))[d4];
    vv[u] = ((const float4*)(V + ((size_t)h * N_ + row) * 64))[d4];
  }
  __syncthreads();

  float4 q4[16], acc[16];
  const float4* qp = (const float4*)(Q + ((size_t)h * N_ + r) * 64);
#pragma unroll
  for (int d = 0; d < 16; ++d) { q4[d] = qp[d]; acc[d] = make_float4(0.f, 0.f, 0.f, 0.f); }

  float ssum = 0.f;
  const int nk = min(SINK_, r + 1);
  for (int j = 0; j < nk; ++j) {
    float s = 0.f;
#pragma unroll
    for (int d = 0; d < 16; ++d) {
      float4 x = q4[d], y = kk[j * 16 + d];
      s = fmaf(x.x, y.x, s); s = fmaf(x.y, y.y, s);
      s = fmaf(x.z, y.z, s); s = fmaf(x.w, y.w, s);
    }
    const float wgt = __expf(fmaf(s, SCALE_, -M0_));
    ssum += wgt;
    const float4* v4 = &vv[j * 16];
#pragma unroll
    for (int d = 0; d < 16; ++d) {
      acc[d].x = fmaf(wgt, v4[d].x, acc[d].x);
      acc[d].y = fmaf(wgt, v4[d].y, acc[d].y);
      acc[d].z = fmaf(wgt, v4[d].z, acc[d].z);
      acc[d].w = fmaf(wgt, v4[d].w, acc[d].w);
    }
  }
  const float pl = M0_ + __logf(ssum);
  const float inv = 1.f / ssum;
  float4* op = (float4*)(out + ((size_t)h * N_ + r) * 64);
  if (r < SINK_) {
#pragma unroll
    for (int d = 0; d < 16; ++d)
      op[d] = make_float4(acc[d].x * inv, acc[d].y * inv, acc[d].z * inv, acc[d].w * inv);
    return;
  }

  const int t = r - SINK_;
  float a[64];
  {
    const uint4* tp = (const uint4*)(tailb + ((size_t)h * NT_ + t) * 64);
#pragma unroll
    for (int j = 0; j < 8; ++j) {
      const uint4 u = tp[j];
      a[8*j+0] = bl_(u.x); a[8*j+1] = bh_(u.x);
      a[8*j+2] = bl_(u.y); a[8*j+3] = bh_(u.y);
      a[8*j+4] = bl_(u.z); a[8*j+5] = bh_(u.z);
      a[8*j+6] = bl_(u.w); a[8*j+7] = bh_(u.w);
    }
  }
  float al = tail_lse[h * NT_ + t];

  const int pp = (t >= NL_) ? 1 : 0;
  const int tloc = t - pp * NL_;
  if (tloc >= 1016) {   // P2 merge (split-K halves combined exactly, then into P1)
    const int vh = h * 2 + pp, i = tloc - 1016;
    const float l20 = lse2[vh * 1016 + i];
    const float l21 = lse2[32 * 1016 + vh * 1016 + i];
    const float c12 = 1.f / (1.f + __expf(l21 - l20));
    const float l2 = logaddexpf_(l20, l21);
    const float c = 1.f / (1.f + __expf(l2 - al));
    const uint4* b0 = (const uint4*)(attn2b + ((size_t)(vh * 1016 + i)) * 64);
    const uint4* b1 = (const uint4*)(attn2b + ((size_t)(32 * 1016 + vh * 1016 + i)) * 64);
#pragma unroll
    for (int j = 0; j < 8; ++j) {
      const uint4 u0 = b0[j], u1 = b1[j];
      float x0[8] = {bl_(u0.x), bh_(u0.x), bl_(u0.y), bh_(u0.y), bl_(u0.z), bh_(u0.z), bl_(u0.w), bh_(u0.w)};
      float x1[8] = {bl_(u1.x), bh_(u1.x), bl_(u1.y), bh_(u1.y), bl_(u1.z), bh_(u1.z), bl_(u1.w), bh_(u1.w)};
#pragma unroll
      for (int e = 0; e < 8; ++e) {
        const float bb = c12 * x0[e] + (1.f - c12) * x1[e];
        a[8*j+e] = c * a[8*j+e] + (1.f - c) * bb;
      }
    }
    al = logaddexpf_(al, l2);
  }
  if (t >= NL_) {       // LSH merge: add_self(block, res), then into tail
    const int qi = t - NL_;
    const float l3a = lse3[h * NL_ + qi];
    const float l3b = lse3[16 * NL_ + h * NL_ + qi];
    const float c34 = 1.f / (1.f + __expf(l3b - l3a));
    const float l3 = logaddexpf_(l3a, l3b);
    const float c = 1.f / (1.f + __expf(l3 - al));
    const uint4* b0 = (const uint4*)(attn3b + ((size_t)(h * NL_ + qi)) * 64);
    const uint4* b1 = (const uint4*)(attn3b + ((size_t)(16 * NL_ + h * NL_ + qi)) * 64);
#pragma unroll
    for (int j = 0; j < 8; ++j) {
      const uint4 u0 = b0[j], u1 = b1[j];
      float x0[8] = {bl_(u0.x), bh_(u0.x), bl_(u0.y), bh_(u0.y), bl_(u0.z), bh_(u0.z), bl_(u0.w), bh_(u0.w)};
      float x1[8] = {bl_(u1.x), bh_(u1.x), bl_(u1.y), bh_(u1.y), bl_(u1.z), bh_(u1.z), bl_(u1.w), bh_(u1.w)};
#pragma unroll
      for (int e = 0; e < 8; ++e) {
        const float bb = c34 * x0[e] + (1.f - c34) * x1[e];
        a[8*j+e] = c * a[8*j+e] + (1.f - c) * bb;
      }
    }
    al = logaddexpf_(al, l3);
  }
  const float cc = 1.f / (1.f + __expf(al - pl));
#pragma unroll
  for (int d = 0; d < 16; ++d)
    op[d] = make_float4(cc * acc[d].x * inv + (1.f - cc) * a[4*d+0],
                        cc * acc[d].y * inv + (1.f - cc) * a[4*d+1],
                        cc * acc[d].z * inv + (1.f - cc) * a[4*d+2],
                        cc * acc[d].w * inv + (1.f - cc) * a[4*d+3]);
}

// ---------------- host ----------------
extern "C" void kernel_launch(void* const* d_in, const int* in_sizes, int n_in,
                              void* d_out, int out_size, void* d_ws, size_t ws_size,
                              hipStream_t stream) {
  (void)in_sizes; (void)n_in; (void)out_size; (void)ws_size;
  const float* Q = (const float*)d_in[0];
  const float* K = (const float*)d_in[1];
  const float* V = (const float*)d_in[2];
  const float* proj = (const float*)d_in[3];
  float* out = (float*)d_out;

  char* w = (char*)d_ws;
  auto carve = [&](size_t bytes) { char* p = w; w += (bytes + 255) & ~(size_t)255; return p; };
  ushort* tailb  = (ushort*)carve((size_t)H_ * NT_ * 64 * sizeof(ushort));
  float* tail_lse = (float*)carve((size_t)H_ * NT_ * sizeof(float));
  ushort* attn2b = (ushort*)carve((size_t)2 * 32 * 1016 * 64 * sizeof(ushort));
  float* lse2    = (float*)carve((size_t)2 * 32 * 1016 * sizeof(float));
  ushort* attn3b = (ushort*)carve((size_t)2 * H_ * NL_ * 64 * sizeof(ushort));
  float* lse3    = (float*)carve((size_t)2 * H_ * NL_ * sizeof(float));
  ushort* Kb     = (ushort*)carve((size_t)H_ * N_ * 64 * sizeof(ushort));
  ushort* Vb     = (ushort*)carve((size_t)H_ * N_ * 64 * sizeof(ushort));
  ushort* Vt     = (ushort*)carve((size_t)H_ * N_ * 64 * sizeof(ushort) + 4096);
  int* hq        = (int*)carve((size_t)H_ * NL_ * sizeof(int));
  int* hk        = (int*)carve((size_t)H_ * NL_ * sizeof(int));
  int* q_sort    = (int*)carve((size_t)H_ * NL_ * sizeof(int));
  int* k_sort    = (int*)carve((size_t)H_ * NL_ * sizeof(int));
  int* samp_pos  = (int*)carve((size_t)H_ * SAMP_ * sizeof(int));
  int* samp_orig = (int*)carve((size_t)H_ * SAMP_ * sizeof(int));

  kern_packhash<<<dim3(3328), 256, 0, stream>>>(K, V, Q, proj, Kb, Vb, Vt, hq, hk);
  kern_sortsamp<<<dim3(H_, 2), 256, 0, stream>>>(hq, hk, q_sort, k_sort, samp_pos, samp_orig);
  kern_attn_mfma<<<dim3(1024), 256, 0, stream>>>(Q, Kb, Vt, tailb, tail_lse, attn2b, lse2);
  kern_lsh_mfma<<<dim3(512), 256, 0, stream>>>(Q, Kb, Vb, q_sort, k_sort, samp_pos, samp_orig,
                                               attn3b, lse3);
  kern_final<<<dim3(H_, 16), 256, 0, stream>>>(Q, K, V, tailb, tail_lse,
                                               attn2b, lse2, attn3b, lse3, out);
}

// Round 15
// 127.711 us; speedup vs baseline: 1.0811x; 1.0010x over previous
//
#include <hip/hip_runtime.h>
#include <hip/hip_bf16.h>
#include <math.h>
#include <stdint.h>

#define H_ 16
#define N_ 4096
#define NT_ 4064        // tail length
#define NL_ 2032        // LSH segment length
#define SINK_ 32
#define SAMP_ 256
#define SCALE_ 0.125f
#define QSCALE_ 0.18033688f    // 0.125 * log2(e)
#define M0L2_ 11.5415606f      // 8 * log2(e)
#define M0_ 8.0f
#define NEGBIG_ -3.0e38f
#define LOGOFF_L2_ 2.9886841f  // log2(2032/256)

typedef unsigned int uint;
typedef unsigned short ushort;
typedef short bf16x8 __attribute__((ext_vector_type(8)));
typedef float f32x4 __attribute__((ext_vector_type(4)));

union B8 { uint4 u; bf16x8 b; };

__device__ __forceinline__ f32x4 mfma16(const B8& a, const B8& b, f32x4 c) {
  return __builtin_amdgcn_mfma_f32_16x16x32_bf16(a.b, b.b, c, 0, 0, 0);
}

__device__ __forceinline__ uint bfpack(float a, float b) {
  uint ua = __float_as_uint(a), ub = __float_as_uint(b);
  ua += 0x7fffu + ((ua >> 16) & 1u);
  ub += 0x7fffu + ((ub >> 16) & 1u);
  return (ua >> 16) | (ub & 0xffff0000u);
}

__device__ __forceinline__ uint cvtpk(float a, float b) {
  union { __hip_bfloat162 h; uint u; } r;
  r.h.x = __float2bfloat16(a);
  r.h.y = __float2bfloat16(b);
  return r.u;
}

__device__ __forceinline__ float bl_(uint u) { return __uint_as_float(u << 16); }
__device__ __forceinline__ float bh_(uint u) { return __uint_as_float(u & 0xffff0000u); }

__device__ __forceinline__ float logaddexpf_(float a, float b) {
  float mx = fmaxf(a, b);
  return mx + __logf(__expf(a - mx) + __expf(b - mx));
}

__device__ __forceinline__ uint32_t rotl32_(uint32_t v, uint32_t d) {
  return (v << d) | (v >> (32u - d));
}

// JAX threefry2x32 (20 rounds)
__device__ inline void tf2x32(uint32_t k0, uint32_t k1, uint32_t& x0, uint32_t& x1) {
  uint32_t ks2 = k0 ^ k1 ^ 0x1BD11BDAu;
  x0 += k0; x1 += k1;
#define TFR(r) { x0 += x1; x1 = rotl32_(x1, r); x1 ^= x0; }
  TFR(13u) TFR(15u) TFR(26u) TFR(6u)
  x0 += k1;  x1 += ks2 + 1u;
  TFR(17u) TFR(29u) TFR(16u) TFR(24u)
  x0 += ks2; x1 += k0 + 2u;
  TFR(13u) TFR(15u) TFR(26u) TFR(6u)
  x0 += k0;  x1 += k1 + 3u;
  TFR(17u) TFR(29u) TFR(16u) TFR(24u)
  x0 += k1;  x1 += ks2 + 4u;
  TFR(13u) TFR(15u) TFR(26u) TFR(6u)
  x0 += ks2; x1 += k0 + 5u;
#undef TFR
}

// ---------------- fixed-offset softmax ----------------
__device__ __forceinline__ void nomax_sm(f32x4 s[4], float& ssum) {
#pragma unroll
  for (int st = 0; st < 4; ++st)
#pragma unroll
    for (int r = 0; r < 4; ++r) {
      s[st][r] = __builtin_exp2f(s[st][r]);
      ssum += s[st][r];
    }
}

// pbuf XOR-swizzled write/read (R4-proven): per-wave 1024B region, per-q 64B row
#define PB_WRITE(SS, HK2) { \
  const f32x4 pa_ = SS[2*(HK2)], pc_ = SS[2*(HK2)+1]; \
  *(uint2*)(pw + ((((g >> 1)    ) ^ (q & 3)) * 16) + (g & 1) * 8) = \
      make_uint2(cvtpk(pa_[0], pa_[1]), cvtpk(pa_[2], pa_[3])); \
  *(uint2*)(pw + (((2 + (g >> 1)) ^ (q & 3)) * 16) + (g & 1) * 8) = \
      make_uint2(cvtpk(pc_[0], pc_[1]), cvtpk(pc_[2], pc_[3])); }
#define PB_READ(PF) { (PF).u = *(const uint4*)(pw + ((g ^ (q & 3)) * 16)); }

// bf16 epilogue store
__device__ __forceinline__ void store_o_bf16(ushort* tp, const f32x4 o[4], float inv, int g) {
#pragma unroll
  for (int d = 0; d < 4; ++d) {
    const f32x4 r = o[d] * inv;
    *(uint2*)(tp + d * 16 + 4 * g) = make_uint2(cvtpk(r[0], r[1]), cvtpk(r[2], r[3]));
  }
}

// =========================================================================
// pack: blocks 0..2047 K bf16 linear; 2048..3071 V transpose; 3072..3327 hash.
// =========================================================================
__global__ __launch_bounds__(256) void kern_packhash(
    const float* __restrict__ K, const float* __restrict__ V, const float* __restrict__ Q,
    const float* __restrict__ proj,
    ushort* __restrict__ Kb, ushort* __restrict__ Vb, ushort* __restrict__ Vt,
    int* __restrict__ hq, int* __restrict__ hk) {
  const int bb = blockIdx.x;
  const int tid = threadIdx.x;
  if (bb < 2048) {               // ---- K linear pack ----
    const size_t idx = (size_t)bb * 256 + tid;
    const float4* s = (const float4*)(K + idx * 8);
    float4 f0 = s[0], f1 = s[1];
    uint4 p = make_uint4(bfpack(f0.x, f0.y), bfpack(f0.z, f0.w),
                         bfpack(f1.x, f1.y), bfpack(f1.z, f1.w));
    *(uint4*)(Kb + idx * 8) = p;
    return;
  }
  if (bb < 3072) {               // ---- V transpose + row pack ----
    __shared__ ushort tr[64 * 72];
    const int u = bb - 2048;
    const int h = u >> 6, nt = u & 63;
    const int n0 = nt * 64;
    const size_t hN = (size_t)h * N_;
    const int nloc = tid >> 2, dpart = (tid & 3) * 16;
    const float4* src = (const float4*)(V + (hN + n0 + nloc) * 64 + dpart);
    float4 f0 = src[0], f1 = src[1], f2 = src[2], f3 = src[3];
    uint p0 = bfpack(f0.x, f0.y), p1 = bfpack(f0.z, f0.w);
    uint p2 = bfpack(f1.x, f1.y), p3 = bfpack(f1.z, f1.w);
    uint p4 = bfpack(f2.x, f2.y), p5 = bfpack(f2.z, f2.w);
    uint p6 = bfpack(f3.x, f3.y), p7 = bfpack(f3.z, f3.w);
    ushort* vbdst = Vb + (hN + n0 + nloc) * 64 + dpart;
    ((uint4*)vbdst)[0] = make_uint4(p0, p1, p2, p3);
    ((uint4*)vbdst)[1] = make_uint4(p4, p5, p6, p7);
    uint pv[8] = {p0, p1, p2, p3, p4, p5, p6, p7};
#pragma unroll
    for (int j = 0; j < 8; ++j) {
      tr[(dpart + 2 * j    ) * 72 + nloc] = (ushort)(pv[j] & 0xffffu);
      tr[(dpart + 2 * j + 1) * 72 + nloc] = (ushort)(pv[j] >> 16);
    }
    __syncthreads();
    const int d = tid >> 2, np = (tid & 3) * 16;
    const uint4* tp = (const uint4*)(tr + d * 72 + np);
    uint4 t0 = tp[0], t1 = tp[1];
    ushort* dst = Vt + ((size_t)(h * 64 + d)) * 4096 + n0 + np;
    ((uint4*)dst)[0] = t0;
    ((uint4*)dst)[1] = t1;
    return;
  }
  // ---- hash ----
  __shared__ float pr[448];
  const int u = bb - 3072;
  const int h = u & 15, tile = (u >> 4) & 7, which = u >> 7;
  for (int t = tid; t < 448; t += 256) pr[t] = proj[t];
  __syncthreads();
  const int i = tile * 256 + tid;
  if (i >= NL_) return;
  const int orig = (which == 0) ? (SINK_ + NL_ + i) : (SINK_ + i);
  const float4* x = (const float4*)((which == 0 ? Q : K) + ((size_t)h * N_ + orig) * 64);
  float xr[64];
#pragma unroll
  for (int d = 0; d < 16; ++d) {
    float4 g = x[d];
    xr[4*d+0] = g.x; xr[4*d+1] = g.y; xr[4*d+2] = g.z; xr[4*d+3] = g.w;
  }
  int bin = 0;
#pragma unroll
  for (int r = 0; r < 7; ++r) {
    float acc = 0.f;
#pragma unroll
    for (int d = 0; d < 64; ++d) acc = fmaf(xr[d], pr[d * 7 + r], acc);
    if (acc > 0.f) bin |= (1 << r);
  }
  const int g = bin ^ (bin >> 1);
  (which == 0 ? hq : hk)[h * NL_ + i] = g;
}

// ---------------- chunked stable counting sort + threefry sample ----------------
__global__ __launch_bounds__(256) void kern_sortsamp(
    const int* __restrict__ hq, const int* __restrict__ hk,
    int* __restrict__ q_sort, int* __restrict__ k_sort,
    int* __restrict__ samp_pos, int* __restrict__ samp_orig) {
  const int h = blockIdx.x, which = blockIdx.y;
  const int tid = threadIdx.x;

  __shared__ unsigned char keys8[NL_];
  __shared__ ushort M[64 * 130];
  __shared__ int btot[128];
  __shared__ int bscan[128];
  __shared__ ushort srt[NL_];

  const int* src = (which == 0 ? hq : hk) + h * NL_;
  for (int u = tid; u < 64 * 130 / 2; u += 256) ((uint*)M)[u] = 0u;
  for (int u = tid; u < NL_; u += 256) keys8[u] = (unsigned char)src[u];
  __syncthreads();

  if (tid < 64) {
    const int c = tid;
#pragma unroll 4
    for (int j = 0; j < 32; ++j) {
      const int u = c * 32 + j;
      if (u < NL_) ++M[c * 130 + keys8[u]];
    }
  }
  __syncthreads();

  if (tid < 128) {
    const int b = tid;
    int run = 0;
    for (int c = 0; c < 64; ++c) {
      const int v = M[c * 130 + b];
      M[c * 130 + b] = (ushort)run;
      run += v;
    }
    btot[b] = run;
    bscan[b] = run;
  }
  __syncthreads();

  for (int ofs = 1; ofs < 128; ofs <<= 1) {
    int v = 0;
    if (tid < 128 && tid >= ofs) v = bscan[tid - ofs];
    __syncthreads();
    if (tid < 128) bscan[tid] += v;
    __syncthreads();
  }

  int* dst = (which == 0 ? q_sort : k_sort) + h * NL_;
  if (tid < 64) {
    const int c = tid;
    for (int j = 0; j < 32; ++j) {
      const int u = c * 32 + j;
      if (u < NL_) {
        const int k = keys8[u];
        const int pos = (bscan[k] - btot[k]) + M[c * 130 + k];
        M[c * 130 + k] += 1;
        dst[pos] = u;
        srt[pos] = (ushort)u;
      }
    }
  }
  __syncthreads();

  if (which == 1) {
    const int s = tid;
    uint32_t a0 = 0u, a1 = 0u; tf2x32(0u, 1234u, a0, a1);
    uint32_t b0 = 0u, b1 = 0u; tf2x32(a0, a1, b0, b1);
    uint32_t c0 = 0u, c1 = 1u; tf2x32(a0, a1, c0, c1);
    const uint32_t j = (uint32_t)(h * SAMP_ + s);
    uint32_t h0 = 0u, h1 = j; tf2x32(b0, b1, h0, h1);
    uint32_t l0 = 0u, l1 = j; tf2x32(c0, c1, l0, l1);
    const uint32_t Hb = h0 ^ h1, Lb = l0 ^ l1;
    const uint32_t off = ((Hb % 2032u) * 16u + (Lb % 2032u)) % 2032u;
    samp_pos[h * SAMP_ + s] = (int)off;
    samp_orig[h * SAMP_ + s] = (int)srt[off];
  }
}

// =========================================================================
// MFMA flash attention (R14 structure; setprio only on PV). Grid 1024.
// LDS: kk 18432 + vv 17408 + pbuf 4096 = 39936 B.
// =========================================================================
__global__ __launch_bounds__(256) void kern_attn_mfma(
    const float* __restrict__ Q, const ushort* __restrict__ Kb, const ushort* __restrict__ Vt,
    ushort* __restrict__ tailb, float* __restrict__ tail_lse,
    ushort* __restrict__ attn2b, float* __restrict__ lse2) {
  __shared__ uint kk[4608];    // 18432 B
  __shared__ uint vv[4352];    // 17408 B
  __shared__ uint pbuf[1024];  // 4096 B

  const int b = blockIdx.x;
  const int tid = threadIdx.x;
  const int lane = tid & 63, w = tid >> 6;
  const int g = lane >> 4, q = lane & 15;
  const uint4 z4 = make_uint4(0, 0, 0, 0);
  const f32x4 accb = {-M0L2_, -M0L2_, -M0L2_, -M0L2_};

  int h, q0, qbase, kbase, ntiles, klen, p2slot = 0, chunkc = 0;
  bool causal;
  if (b < 512) {                       // P1: LPT descending qt
    const int u = b; const int vh = u & 63;
    const int qt = 7 - (u >> 6);
    h = vh >> 2; chunkc = vh & 3;
    q0 = qt * 128;
    qbase = SINK_ + chunkc * 1016;
    kbase = qbase;
    ntiles = qt + 1; causal = true; klen = 1016;
  } else {                             // P2 split-K halves
    const int u = b - 512; const int vh = u & 31; const int qt = (u >> 5) & 7;
    const int hf = u >> 8;
    h = vh >> 1; const int pp = vh & 1;
    q0 = qt * 128;
    qbase = SINK_ + pp * 2032 + 1016;
    kbase = SINK_ + pp * 2032 + hf * 512;
    ntiles = 4; causal = false; klen = hf ? 504 : 512;
    p2slot = hf * 32 * 1016 + vh * 1016;
  }
  const size_t hN = (size_t)h * N_;
  const int qrowA = q0 + w * 16 + q;
  const int qrowB = qrowA + 64;
  const int qcA = min(qrowA, 1015), qcB = min(qrowB, 1015);
  const int qwA_lo = q0 + w * 16, qwmaxA = qwA_lo + 15;
  const int qwB_lo = qwA_lo + 64;

  B8 qbA0, qbA1, qbB0, qbB1;
  {
    const float4* qp = (const float4*)(Q + (hN + qbase + qcA) * 64);
    float4 a = qp[2*g], c = qp[2*g+1], d = qp[8+2*g], e = qp[8+2*g+1];
    qbA0.u = make_uint4(bfpack(a.x*QSCALE_, a.y*QSCALE_), bfpack(a.z*QSCALE_, a.w*QSCALE_),
                        bfpack(c.x*QSCALE_, c.y*QSCALE_), bfpack(c.z*QSCALE_, c.w*QSCALE_));
    qbA1.u = make_uint4(bfpack(d.x*QSCALE_, d.y*QSCALE_), bfpack(d.z*QSCALE_, d.w*QSCALE_),
                        bfpack(e.x*QSCALE_, e.y*QSCALE_), bfpack(e.z*QSCALE_, e.w*QSCALE_));
    const float4* qp2 = (const float4*)(Q + (hN + qbase + qcB) * 64);
    a = qp2[2*g]; c = qp2[2*g+1]; d = qp2[8+2*g]; e = qp2[8+2*g+1];
    qbB0.u = make_uint4(bfpack(a.x*QSCALE_, a.y*QSCALE_), bfpack(a.z*QSCALE_, a.w*QSCALE_),
                        bfpack(c.x*QSCALE_, c.y*QSCALE_), bfpack(c.z*QSCALE_, c.w*QSCALE_));
    qbB1.u = make_uint4(bfpack(d.x*QSCALE_, d.y*QSCALE_), bfpack(d.z*QSCALE_, d.w*QSCALE_),
                        bfpack(e.x*QSCALE_, e.y*QSCALE_), bfpack(e.z*QSCALE_, e.w*QSCALE_));
  }
  f32x4 oA[4] = {{0,0,0,0},{0,0,0,0},{0,0,0,0},{0,0,0,0}};
  f32x4 oB[4] = {{0,0,0,0},{0,0,0,0},{0,0,0,0},{0,0,0,0}};
  float ssA = 0.f, ssB = 0.f;

  const int krow_l = tid >> 1, kpart = tid & 1;
  const int vrow = tid >> 2, vc32 = tid & 3;
  char* kdst = (char*)kk + krow_l * 144 + kpart * 64;
  char* vdst = (char*)vv + vrow * 272 + vc32 * 64;
  const char* kq = (const char*)kk + q * 144 + g * 16;
  const char* vq = (const char*)vv + q * 272 + g * 16;
  char* pw = (char*)pbuf + w * 1024 + q * 64;
  const size_t vtbase = ((size_t)(h * 64 + vrow)) * 4096 + kbase + vc32 * 32;

  uint4 kp0, kp1, kp2, kp3, va, va2, vb_, vb2;

#define LOADK(T) { const int kr = (T) * 128 + krow_l; \
    if (kr < klen) { const uint4* s = (const uint4*)(Kb + (hN + kbase + kr) * 64 + kpart * 32); \
      kp0 = s[0]; kp1 = s[1]; kp2 = s[2]; kp3 = s[3]; } \
    else { kp0 = z4; kp1 = z4; kp2 = z4; kp3 = z4; } }
#define LOADV(T) { const uint4* sv = (const uint4*)(Vt + vtbase + (size_t)(T) * 128); \
    va = sv[0]; va2 = sv[1]; vb_ = sv[2]; vb2 = sv[3]; }

  LOADK(0) LOADV(0)

  for (int t = 0; t < ntiles; ++t) {
    const int kt = t * 128;
    __syncthreads();
    *(uint4*)kdst = kp0; *(uint4*)(kdst + 16) = kp1;
    *(uint4*)(kdst + 32) = kp2; *(uint4*)(kdst + 48) = kp3;
    *(uint4*)vdst = va; *(uint4*)(vdst + 16) = va2;
    *(uint4*)(vdst + 32) = vb_; *(uint4*)(vdst + 48) = vb2;
    __syncthreads();
    if (t + 1 < ntiles) { LOADK(t + 1) LOADV(t + 1) }

#pragma unroll
    for (int u2 = 0; u2 < 2; ++u2) {
      const int hb = kt + u2 * 64;
      const bool dA = !(causal && hb > qwmaxA);
      f32x4 sA[4], sB[4];
#pragma unroll
      for (int st = 0; st < 4; ++st) {
        B8 ka, kb2;
        ka.u  = *(const uint4*)(kq + (u2 * 64 + st * 16) * 144);
        kb2.u = *(const uint4*)(kq + (u2 * 64 + st * 16) * 144 + 64);
        if (dA) {
          f32x4 acc = accb;
          acc = mfma16(ka, qbA0, acc); acc = mfma16(kb2, qbA1, acc);
          sA[st] = acc;
        }
        f32x4 acc2 = accb;
        acc2 = mfma16(ka, qbB0, acc2); acc2 = mfma16(kb2, qbB1, acc2);
        sB[st] = acc2;
      }

      if (causal) {
        const int kb0 = hb + 4 * g;
        if (dA && hb + 63 > qwA_lo) {
#pragma unroll
          for (int st = 0; st < 4; ++st)
#pragma unroll
            for (int r = 0; r < 4; ++r)
              if (kb0 + st * 16 + r > qrowA) sA[st][r] = NEGBIG_;
        }
        if (hb + 63 > qwB_lo) {
#pragma unroll
          for (int st = 0; st < 4; ++st)
#pragma unroll
            for (int r = 0; r < 4; ++r)
              if (kb0 + st * 16 + r > qrowB) sB[st][r] = NEGBIG_;
        }
      } else if (hb + 63 >= klen) {
        const int kb0 = hb + 4 * g;
#pragma unroll
        for (int st = 0; st < 4; ++st)
#pragma unroll
          for (int r = 0; r < 4; ++r)
            if (kb0 + st * 16 + r >= klen) { sA[st][r] = NEGBIG_; sB[st][r] = NEGBIG_; }
      }

      if (dA) {
        nomax_sm(sA, ssA);
        nomax_sm(sB, ssB);
        __builtin_amdgcn_s_setprio(1);
#pragma unroll
        for (int hk2 = 0; hk2 < 2; ++hk2) {
          B8 pfA, pfB, vf;
          PB_WRITE(sA, hk2) PB_READ(pfA)
          PB_WRITE(sB, hk2) PB_READ(pfB)
          const int vo = u2 * 128 + hk2 * 64;
          vf.u = *(const uint4*)(vq + 0 * 4352 + vo);
          oA[0] = mfma16(vf, pfA, oA[0]); oB[0] = mfma16(vf, pfB, oB[0]);
          vf.u = *(const uint4*)(vq + 1 * 4352 + vo);
          oA[1] = mfma16(vf, pfA, oA[1]); oB[1] = mfma16(vf, pfB, oB[1]);
          vf.u = *(const uint4*)(vq + 2 * 4352 + vo);
          oA[2] = mfma16(vf, pfA, oA[2]); oB[2] = mfma16(vf, pfB, oB[2]);
          vf.u = *(const uint4*)(vq + 3 * 4352 + vo);
          oA[3] = mfma16(vf, pfA, oA[3]); oB[3] = mfma16(vf, pfB, oB[3]);
        }
        __builtin_amdgcn_s_setprio(0);
      } else {
        nomax_sm(sB, ssB);
        __builtin_amdgcn_s_setprio(1);
#pragma unroll
        for (int hk2 = 0; hk2 < 2; ++hk2) {
          B8 pfB, vf;
          PB_WRITE(sB, hk2) PB_READ(pfB)
          const int vo = u2 * 128 + hk2 * 64;
          vf.u = *(const uint4*)(vq + 0 * 4352 + vo); oB[0] = mfma16(vf, pfB, oB[0]);
          vf.u = *(const uint4*)(vq + 1 * 4352 + vo); oB[1] = mfma16(vf, pfB, oB[1]);
          vf.u = *(const uint4*)(vq + 2 * 4352 + vo); oB[2] = mfma16(vf, pfB, oB[2]);
          vf.u = *(const uint4*)(vq + 3 * 4352 + vo); oB[3] = mfma16(vf, pfB, oB[3]);
        }
        __builtin_amdgcn_s_setprio(0);
      }
    }
  }
#undef LOADK
#undef LOADV

  ssA += __shfl_xor(ssA, 16); ssA += __shfl_xor(ssA, 32);
  ssB += __shfl_xor(ssB, 16); ssB += __shfl_xor(ssB, 32);
#pragma unroll
  for (int fr = 0; fr < 2; ++fr) {
    const int qrow = fr == 0 ? qrowA : qrowB;
    if (qrow >= 1016) continue;
    f32x4* o = fr == 0 ? oA : oB;
    const float ss = fr == 0 ? ssA : ssB;
    const float lse = M0_ + __logf(ss);
    const float inv = 1.f / ss;
    if (causal) {
      const int trow = chunkc * 1016 + qrow;
      store_o_bf16(tailb + ((size_t)h * NT_ + trow) * 64, o, inv, g);
      if (lane < 16) tail_lse[h * NT_ + trow] = lse;
    } else {
      store_o_bf16(attn2b + ((size_t)(p2slot + qrow)) * 64, o, inv, g);
      if (lane < 16) lse2[p2slot + qrow] = lse;
    }
  }
}

// =========================================================================
// MFMA LSH attention (setprio only on PV). Grid 512 -> attn3b (bf16).
// =========================================================================
__global__ __launch_bounds__(256) void kern_lsh_mfma(
    const float* __restrict__ Q, const ushort* __restrict__ Kb, const ushort* __restrict__ Vb,
    const int* __restrict__ q_sort, const int* __restrict__ k_sort,
    const int* __restrict__ samp_pos, const int* __restrict__ samp_orig,
    ushort* __restrict__ attn3b, float* __restrict__ lse3) {
  __shared__ uint kk[2304];
  __shared__ uint vv[2304];
  __shared__ uint pbuf[1024];
  __shared__ float bias_s[64];

  const int b = blockIdx.x;
  const int which = b >> 8;
  const int bq = b & 255;
  const int h = bq >> 4, pt = bq & 15;
  const int tid = threadIdx.x;
  const int lane = tid & 63, w = tid >> 6;
  const int g = lane >> 4, q = lane & 15;
  const int blkq = pt >> 1;
  const size_t hN = (size_t)h * N_;

  const int pA = pt * 128 + w * 16 + q;
  const int pB = pA + 64;
  const int qiA = q_sort[h * NL_ + min(pA, NL_ - 1)];
  const int qiB = q_sort[h * NL_ + min(pB, NL_ - 1)];

  const int skey = tid >> 2, kpart = tid & 3;
  const int kpi = tid & 31, vdb = (tid >> 5) * 8;
  int kidx[4], vi0[4], vi1[4];
  float biasr[4];
#pragma unroll
  for (int t = 0; t < 4; ++t) {
    if (which == 0) {
      const int slot = blkq * 256 + t * 64 + skey;
      kidx[t] = (slot < NL_) ? k_sort[h * NL_ + slot] : -1;
      const int s0 = blkq * 256 + t * 64 + 2 * kpi;
      vi0[t] = (s0 < NL_) ? k_sort[h * NL_ + s0] : -1;
      vi1[t] = (s0 + 1 < NL_) ? k_sort[h * NL_ + s0 + 1] : -1;
    } else {
      kidx[t] = samp_orig[h * SAMP_ + t * 64 + skey];
      const int si = t * 64 + 2 * kpi;
      vi0[t] = samp_orig[h * SAMP_ + si];
      vi1[t] = samp_orig[h * SAMP_ + si + 1];
    }
  }
  if (which == 1 && tid < 64) {
#pragma unroll
    for (int j = 0; j < 4; ++j)
      biasr[j] = ((samp_pos[h * SAMP_ + j * 64 + tid] >> 8) == blkq) ? NEGBIG_ : LOGOFF_L2_;
  }

  B8 qbA0, qbA1, qbB0, qbB1;
  {
    const float4* qp = (const float4*)(Q + (hN + SINK_ + NL_ + qiA) * 64);
    float4 a = qp[2*g], c = qp[2*g+1], d = qp[8+2*g], e = qp[8+2*g+1];
    qbA0.u = make_uint4(bfpack(a.x*QSCALE_, a.y*QSCALE_), bfpack(a.z*QSCALE_, a.w*QSCALE_),
                        bfpack(c.x*QSCALE_, c.y*QSCALE_), bfpack(c.z*QSCALE_, c.w*QSCALE_));
    qbA1.u = make_uint4(bfpack(d.x*QSCALE_, d.y*QSCALE_), bfpack(d.z*QSCALE_, d.w*QSCALE_),
                        bfpack(e.x*QSCALE_, e.y*QSCALE_), bfpack(e.z*QSCALE_, e.w*QSCALE_));
    const float4* qp2 = (const float4*)(Q + (hN + SINK_ + NL_ + qiB) * 64);
    a = qp2[2*g]; c = qp2[2*g+1]; d = qp2[8+2*g]; e = qp2[8+2*g+1];
    qbB0.u = make_uint4(bfpack(a.x*QSCALE_, a.y*QSCALE_), bfpack(a.z*QSCALE_, a.w*QSCALE_),
                        bfpack(c.x*QSCALE_, c.y*QSCALE_), bfpack(c.z*QSCALE_, c.w*QSCALE_));
    qbB1.u = make_uint4(bfpack(d.x*QSCALE_, d.y*QSCALE_), bfpack(d.z*QSCALE_, d.w*QSCALE_),
                        bfpack(e.x*QSCALE_, e.y*QSCALE_), bfpack(e.z*QSCALE_, e.w*QSCALE_));
  }
  f32x4 oA[4] = {{0,0,0,0},{0,0,0,0},{0,0,0,0},{0,0,0,0}};
  f32x4 oB[4] = {{0,0,0,0},{0,0,0,0},{0,0,0,0},{0,0,0,0}};
  float ssA = 0.f, ssB = 0.f;
  const f32x4 accb = {-M0L2_, -M0L2_, -M0L2_, -M0L2_};

  char* kdst = (char*)kk + skey * 144 + kpart * 32;
  char* vdst = (char*)vv + vdb * 144 + kpi * 4;
  const char* kq = (const char*)kk + q * 144 + g * 16;
  const char* vq = (const char*)vv + q * 144 + g * 16;
  char* pw = (char*)pbuf + w * 1024 + q * 64;

  const uint4 z4 = make_uint4(0, 0, 0, 0);
  uint4 kp0, kp1, va, vb_;

#define LLOADK(T) { const int kr = kidx[T]; \
    if (kr >= 0) { const uint4* s = (const uint4*)(Kb + (hN + SINK_ + kr) * 64 + kpart * 16); \
      kp0 = s[0]; kp1 = s[1]; } else { kp0 = z4; kp1 = z4; } }
#define LLOADV(T) { const int r0 = vi0[T], r1 = vi1[T]; \
    va  = (r0 >= 0) ? *(const uint4*)(Vb + (hN + SINK_ + r0) * 64 + vdb) : z4; \
    vb_ = (r1 >= 0) ? *(const uint4*)(Vb + (hN + SINK_ + r1) * 64 + vdb) : z4; }

  LLOADK(0) LLOADV(0)

  for (int t = 0; t < 4; ++t) {
    __syncthreads();
    *(uint4*)kdst = kp0; *(uint4*)(kdst + 16) = kp1;
#define VP(JW, AW, BW) { \
    *(uint*)(vdst + (2*(JW)) * 144) = (AW & 0xffffu) | (BW << 16); \
    *(uint*)(vdst + (2*(JW) + 1) * 144) = (AW >> 16) | (BW & 0xffff0000u); }
    VP(0, va.x, vb_.x) VP(1, va.y, vb_.y) VP(2, va.z, vb_.z) VP(3, va.w, vb_.w)
#undef VP
    if (which == 1 && tid < 64) bias_s[tid] = biasr[t];
    __syncthreads();
    if (t + 1 < 4) { LLOADK(t + 1) LLOADV(t + 1) }

    f32x4 sA[4], sB[4];
#pragma unroll
    for (int st = 0; st < 4; ++st) {
      B8 ka, kb2;
      ka.u  = *(const uint4*)(kq + (st * 16) * 144);
      kb2.u = *(const uint4*)(kq + (st * 16) * 144 + 64);
      f32x4 acc = accb;
      acc = mfma16(ka, qbA0, acc); acc = mfma16(kb2, qbA1, acc);
      sA[st] = acc;
      f32x4 acc2 = accb;
      acc2 = mfma16(ka, qbB0, acc2); acc2 = mfma16(kb2, qbB1, acc2);
      sB[st] = acc2;
    }
    if (which == 1) {
      const f32x4* bp = (const f32x4*)bias_s;
#pragma unroll
      for (int st = 0; st < 4; ++st) {
        sA[st] = sA[st] + bp[st * 4 + g];
        sB[st] = sB[st] + bp[st * 4 + g];
      }
    }

    nomax_sm(sA, ssA);
    nomax_sm(sB, ssB);
    __builtin_amdgcn_s_setprio(1);
#pragma unroll
    for (int hk2 = 0; hk2 < 2; ++hk2) {
      B8 pfA, pfB, vf;
      PB_WRITE(sA, hk2) PB_READ(pfA)
      PB_WRITE(sB, hk2) PB_READ(pfB)
      const int vo = hk2 * 64;
      vf.u = *(const uint4*)(vq + 0 * 2304 + vo);
      oA[0] = mfma16(vf, pfA, oA[0]); oB[0] = mfma16(vf, pfB, oB[0]);
      vf.u = *(const uint4*)(vq + 1 * 2304 + vo);
      oA[1] = mfma16(vf, pfA, oA[1]); oB[1] = mfma16(vf, pfB, oB[1]);
      vf.u = *(const uint4*)(vq + 2 * 2304 + vo);
      oA[2] = mfma16(vf, pfA, oA[2]); oB[2] = mfma16(vf, pfB, oB[2]);
      vf.u = *(const uint4*)(vq + 3 * 2304 + vo);
      oA[3] = mfma16(vf, pfA, oA[3]); oB[3] = mfma16(vf, pfB, oB[3]);
    }
    __builtin_amdgcn_s_setprio(0);
  }
#undef LLOADK
#undef LLOADV

  ssA += __shfl_xor(ssA, 16); ssA += __shfl_xor(ssA, 32);
  ssB += __shfl_xor(ssB, 16); ssB += __shfl_xor(ssB, 32);
  const size_t obase = (size_t)which * 16 * NL_;
#pragma unroll
  for (int fr = 0; fr < 2; ++fr) {
    const int p = fr == 0 ? pA : pB;
    if (p >= NL_) continue;
    const int qi = fr == 0 ? qiA : qiB;
    f32x4* o = fr == 0 ? oA : oB;
    const float ss = fr == 0 ? ssA : ssB;
    const float un = M0_ + __logf(ss);
    const float inv = 1.f / ss;
    store_o_bf16(attn3b + (obase + (size_t)h * NL_ + qi) * 64, o, inv, g);
    if (lane < 16) lse3[obase + h * NL_ + qi] = un;
  }
}

// ---------------- sink prefix (no-max, ILP) + full ordered merge (bf16 partials) ----------------
// 512 blocks x 128 threads (2 blocks/CU) for better latency hiding.
__global__ __launch_bounds__(128) void kern_final(
    const float* __restrict__ Q, const float* __restrict__ K, const float* __restrict__ V,
    const ushort* __restrict__ tailb, const float* __restrict__ tail_lse,
    const ushort* __restrict__ attn2b, const float* __restrict__ lse2,
    const ushort* __restrict__ attn3b, const float* __restrict__ lse3,
    float* __restrict__ out) {
  const int h = blockIdx.x;
  const int r = blockIdx.y * 128 + (int)threadIdx.x;

  __shared__ float4 kk[SINK_ * 16];
  __shared__ float4 vv[SINK_ * 16];
  for (int u = threadIdx.x; u < SINK_ * 16; u += 128) {
    const int row = u >> 4, d4 = u & 15;
    kk[u] = ((const float4*)(K + ((size_t)h * N_ + row) * 64))[d4];
    vv[u] = ((const float4*)(V + ((size_t)h * N_ + row) * 64))[d4];
  }
  __syncthreads();

  float4 q4[16], acc[16];
  const float4* qp = (const float4*)(Q + ((size_t)h * N_ + r) * 64);
#pragma unroll
  for (int d = 0; d < 16; ++d) { q4[d] = qp[d]; acc[d] = make_float4(0.f, 0.f, 0.f, 0.f); }

  float ssum = 0.f;
  const int nk = min(SINK_, r + 1);
  for (int j = 0; j < nk; ++j) {
    float s = 0.f;
#pragma unroll
    for (int d = 0; d < 16; ++d) {
      float4 x = q4[d], y = kk[j * 16 + d];
      s = fmaf(x.x, y.x, s); s = fmaf(x.y, y.y, s);
      s = fmaf(x.z, y.z, s); s = fmaf(x.w, y.w, s);
    }
    const float wgt = __expf(fmaf(s, SCALE_, -M0_));
    ssum += wgt;
    const float4* v4 = &vv[j * 16];
#pragma unroll
    for (int d = 0; d < 16; ++d) {
      acc[d].x = fmaf(wgt, v4[d].x, acc[d].x);
      acc[d].y = fmaf(wgt, v4[d].y, acc[d].y);
      acc[d].z = fmaf(wgt, v4[d].z, acc[d].z);
      acc[d].w = fmaf(wgt, v4[d].w, acc[d].w);
    }
  }
  const float pl = M0_ + __logf(ssum);
  const float inv = 1.f / ssum;
  float4* op = (float4*)(out + ((size_t)h * N_ + r) * 64);
  if (r < SINK_) {
#pragma unroll
    for (int d = 0; d < 16; ++d)
      op[d] = make_float4(acc[d].x * inv, acc[d].y * inv, acc[d].z * inv, acc[d].w * inv);
    return;
  }

  const int t = r - SINK_;
  float a[64];
  {
    const uint4* tp = (const uint4*)(tailb + ((size_t)h * NT_ + t) * 64);
#pragma unroll
    for (int j = 0; j < 8; ++j) {
      const uint4 u = tp[j];
      a[8*j+0] = bl_(u.x); a[8*j+1] = bh_(u.x);
      a[8*j+2] = bl_(u.y); a[8*j+3] = bh_(u.y);
      a[8*j+4] = bl_(u.z); a[8*j+5] = bh_(u.z);
      a[8*j+6] = bl_(u.w); a[8*j+7] = bh_(u.w);
    }
  }
  float al = tail_lse[h * NT_ + t];

  const int pp = (t >= NL_) ? 1 : 0;
  const int tloc = t - pp * NL_;
  if (tloc >= 1016) {   // P2 merge (split-K halves combined exactly, then into P1)
    const int vh = h * 2 + pp, i = tloc - 1016;
    const float l20 = lse2[vh * 1016 + i];
    const float l21 = lse2[32 * 1016 + vh * 1016 + i];
    const float c12 = 1.f / (1.f + __expf(l21 - l20));
    const float l2 = logaddexpf_(l20, l21);
    const float c = 1.f / (1.f + __expf(l2 - al));
    const uint4* b0 = (const uint4*)(attn2b + ((size_t)(vh * 1016 + i)) * 64);
    const uint4* b1 = (const uint4*)(attn2b + ((size_t)(32 * 1016 + vh * 1016 + i)) * 64);
#pragma unroll
    for (int j = 0; j < 8; ++j) {
      const uint4 u0 = b0[j], u1 = b1[j];
      float x0[8] = {bl_(u0.x), bh_(u0.x), bl_(u0.y), bh_(u0.y), bl_(u0.z), bh_(u0.z), bl_(u0.w), bh_(u0.w)};
      float x1[8] = {bl_(u1.x), bh_(u1.x), bl_(u1.y), bh_(u1.y), bl_(u1.z), bh_(u1.z), bl_(u1.w), bh_(u1.w)};
#pragma unroll
      for (int e = 0; e < 8; ++e) {
        const float bb = c12 * x0[e] + (1.f - c12) * x1[e];
        a[8*j+e] = c * a[8*j+e] + (1.f - c) * bb;
      }
    }
    al = logaddexpf_(al, l2);
  }
  if (t >= NL_) {       // LSH merge: add_self(block, res), then into tail
    const int qi = t - NL_;
    const float l3a = lse3[h * NL_ + qi];
    const float l3b = lse3[16 * NL_ + h * NL_ + qi];
    const float c34 = 1.f / (1.f + __expf(l3b - l3a));
    const float l3 = logaddexpf_(l3a, l3b);
    const float c = 1.f / (1.f + __expf(l3 - al));
    const uint4* b0 = (const uint4*)(attn3b + ((size_t)(h * NL_ + qi)) * 64);
    const uint4* b1 = (const uint4*)(attn3b + ((size_t)(16 * NL_ + h * NL_ + qi)) * 64);
#pragma unroll
    for (int j = 0; j < 8; ++j) {
      const uint4 u0 = b0[j], u1 = b1[j];
      float x0[8] = {bl_(u0.x), bh_(u0.x), bl_(u0.y), bh_(u0.y), bl_(u0.z), bh_(u0.z), bl_(u0.w), bh_(u0.w)};
      float x1[8] = {bl_(u1.x), bh_(u1.x), bl_(u1.y), bh_(u1.y), bl_(u1.z), bh_(u1.z), bl_(u1.w), bh_(u1.w)};
#pragma unroll
      for (int e = 0; e < 8; ++e) {
        const float bb = c34 * x0[e] + (1.f - c34) * x1[e];
        a[8*j+e] = c * a[8*j+e] + (1.f - c) * bb;
      }
    }
    al = logaddexpf_(al, l3);
  }
  const float cc = 1.f / (1.f + __expf(al - pl));
#pragma unroll
  for (int d = 0; d < 16; ++d)
    op[d] = make_float4(cc * acc[d].x * inv + (1.f - cc) * a[4*d+0],
                        cc * acc[d].y * inv + (1.f - cc) * a[4*d+1],
                        cc * acc[d].z * inv + (1.f - cc) * a[4*d+2],
                        cc * acc[d].w * inv + (1.f - cc) * a[4*d+3]);
}

// ---------------- host ----------------
extern "C" void kernel_launch(void* const* d_in, const int* in_sizes, int n_in,
                              void* d_out, int out_size, void* d_ws, size_t ws_size,
                              hipStream_t stream) {
  (void)in_sizes; (void)n_in; (void)out_size; (void)ws_size;
  const float* Q = (const float*)d_in[0];
  const float* K = (const float*)d_in[1];
  const float* V = (const float*)d_in[2];
  const float* proj = (const float*)d_in[3];
  float* out = (float*)d_out;

  char* w = (char*)d_ws;
  auto carve = [&](size_t bytes) { char* p = w; w += (bytes + 255) & ~(size_t)255; return p; };
  ushort* tailb  = (ushort*)carve((size_t)H_ * NT_ * 64 * sizeof(ushort));
  float* tail_lse = (float*)carve((size_t)H_ * NT_ * sizeof(float));
  ushort* attn2b = (ushort*)carve((size_t)2 * 32 * 1016 * 64 * sizeof(ushort));
  float* lse2    = (float*)carve((size_t)2 * 32 * 1016 * sizeof(float));
  ushort* attn3b = (ushort*)carve((size_t)2 * H_ * NL_ * 64 * sizeof(ushort));
  float* lse3    = (float*)carve((size_t)2 * H_ * NL_ * sizeof(float));
  ushort* Kb     = (ushort*)carve((size_t)H_ * N_ * 64 * sizeof(ushort));
  ushort* Vb     = (ushort*)carve((size_t)H_ * N_ * 64 * sizeof(ushort));
  ushort* Vt     = (ushort*)carve((size_t)H_ * N_ * 64 * sizeof(ushort) + 4096);
  int* hq        = (int*)carve((size_t)H_ * NL_ * sizeof(int));
  int* hk        = (int*)carve((size_t)H_ * NL_ * sizeof(int));
  int* q_sort    = (int*)carve((size_t)H_ * NL_ * sizeof(int));
  int* k_sort    = (int*)carve((size_t)H_ * NL_ * sizeof(int));
  int* samp_pos  = (int*)carve((size_t)H_ * SAMP_ * sizeof(int));
  int* samp_orig = (int*)carve((size_t)H_ * SAMP_ * sizeof(int));

  kern_packhash<<<dim3(3328), 256, 0, stream>>>(K, V, Q, proj, Kb, Vb, Vt, hq, hk);
  kern_sortsamp<<<dim3(H_, 2), 256, 0, stream>>>(hq, hk, q_sort, k_sort, samp_pos, samp_orig);
  kern_attn_mfma<<<dim3(1024), 256, 0, stream>>>(Q, Kb, Vt, tailb, tail_lse, attn2b, lse2);
  kern_lsh_mfma<<<dim3(512), 256, 0, stream>>>(Q, Kb, Vb, q_sort, k_sort, samp_pos, samp_orig,
                                               attn3b, lse3);
  kern_final<<<dim3(H_, 32), 128, 0, stream>>>(Q, K, V, tailb, tail_lse,
                                               attn2b, lse2, attn3b, lse3, out);
}